// Round 1
// baseline (9637.188 us; speedup 1.0000x reference)
//
#include <hip/hip_runtime.h>
#include <math.h>

#define B_ 8
#define S_ 128
#define E_ 512
#define D_ 1024
#define H_ 16
#define L_ 4
#define V_ 32000
#define DH_ 64
#define FF_ 4096
#define M_ 1024      // S_*B_ rows, row = s*B_+b
#define ME_ 4096     // E_*B_ rows, row = e*B_+b
#define NT_ 500      // V_/64 vocab tiles
#define SCALE_F 0.125f
#define NEGV (-1e30f)

// ---------------- reductions ----------------
__device__ __forceinline__ float warp_reduce_sum(float v) {
#pragma unroll
  for (int o = 32; o > 0; o >>= 1) v += __shfl_down(v, o);
  return v;
}
__device__ __forceinline__ float warp_reduce_max(float v) {
#pragma unroll
  for (int o = 32; o > 0; o >>= 1) v = fmaxf(v, __shfl_down(v, o));
  return v;
}
// sred must have >= blockDim.x/64 floats; safe for back-to-back calls
__device__ __forceinline__ float block_reduce_sum(float v, float* sred) {
  v = warp_reduce_sum(v);
  __syncthreads();
  if ((threadIdx.x & 63) == 0) sred[threadIdx.x >> 6] = v;
  __syncthreads();
  float s = 0.0f;
  int nw = blockDim.x >> 6;
  for (int w = 0; w < nw; ++w) s += sred[w];
  return s;
}
__device__ __forceinline__ float block_reduce_max(float v, float* sred) {
  v = warp_reduce_max(v);
  __syncthreads();
  if ((threadIdx.x & 63) == 0) sred[threadIdx.x >> 6] = v;
  __syncthreads();
  float s = -3.4e38f;
  int nw = blockDim.x >> 6;
  for (int w = 0; w < nw; ++w) s = fmaxf(s, sred[w]);
  return s;
}

// ---------------- setup kernels ----------------
__global__ __launch_bounds__(256) void pos_emb_kernel(float* __restrict__ r) {
  int t = blockIdx.x * 256 + threadIdx.x;
  if (t >= S_ * D_) return;
  int i = t / D_, j = t % D_;
  float pos = (float)(S_ - 1 - i);
  int jj = (j < D_ / 2) ? j : (j - D_ / 2);
  float invf = powf(10000.0f, -(float)(2 * jj) / (float)D_);
  float a = pos * invf;
  r[t] = (j < D_ / 2) ? sinf(a) : cosf(a);
}

__global__ __launch_bounds__(256) void embed_kernel(const int* __restrict__ ids,
                                                    const float* __restrict__ emb,
                                                    float* __restrict__ core) {
  int t = blockIdx.x * 256 + threadIdx.x;  // over M_*D_
  if (t >= M_ * D_) return;
  int d = t & (D_ - 1);
  int row = t >> 10;       // D_=1024
  int s = row >> 3;        // B_=8
  int b = row & 7;
  core[t] = emb[(size_t)ids[b * S_ + s] * D_ + d];
}

__global__ __launch_bounds__(256) void enc_t_kernel(const float* __restrict__ enc,
                                                    float* __restrict__ enc_t) {
  int t = blockIdx.x * 256 + threadIdx.x;  // over ME_*D_
  if (t >= ME_ * D_) return;
  int d = t & (D_ - 1);
  int row = t >> 10;
  int e = row >> 3;
  int b = row & 7;
  enc_t[t] = enc[((size_t)b * E_ + e) * D_ + d];
}

// ---------------- generic tiled fp32 GEMM: C[M,N] = A[M,K] * W[N,K]^T ----------------
// requires M%64==0, N%64==0, K%16==0
template <bool BIAS, int ACT>
__global__ __launch_bounds__(256) void gemm_kernel(const float* __restrict__ A,
                                                   const float* __restrict__ W,
                                                   const float* __restrict__ bias,
                                                   float* __restrict__ C,
                                                   int M, int N, int K) {
  __shared__ float As[16][65];
  __shared__ float Ws[16][65];
  int tid = threadIdx.x;
  int bn = blockIdx.x * 64;
  int bm = blockIdx.y * 64;
  int tx = tid & 15, ty = tid >> 4;
  float acc[4][4] = {};
  int e = tid * 4;
  int r = e >> 4, kk = e & 15;
  for (int k0 = 0; k0 < K; k0 += 16) {
    float4 av = *(const float4*)(A + (size_t)(bm + r) * K + k0 + kk);
    As[kk + 0][r] = av.x; As[kk + 1][r] = av.y; As[kk + 2][r] = av.z; As[kk + 3][r] = av.w;
    float4 wv = *(const float4*)(W + (size_t)(bn + r) * K + k0 + kk);
    Ws[kk + 0][r] = wv.x; Ws[kk + 1][r] = wv.y; Ws[kk + 2][r] = wv.z; Ws[kk + 3][r] = wv.w;
    __syncthreads();
#pragma unroll
    for (int k2 = 0; k2 < 16; ++k2) {
      float a0[4], b0[4];
#pragma unroll
      for (int i2 = 0; i2 < 4; ++i2) a0[i2] = As[k2][ty * 4 + i2];
#pragma unroll
      for (int j2 = 0; j2 < 4; ++j2) b0[j2] = Ws[k2][tx * 4 + j2];
#pragma unroll
      for (int i2 = 0; i2 < 4; ++i2)
#pragma unroll
        for (int j2 = 0; j2 < 4; ++j2) acc[i2][j2] += a0[i2] * b0[j2];
    }
    __syncthreads();
  }
#pragma unroll
  for (int i2 = 0; i2 < 4; ++i2) {
    int row = bm + ty * 4 + i2;
#pragma unroll
    for (int j2 = 0; j2 < 4; ++j2) {
      int col = bn + tx * 4 + j2;
      float v = acc[i2][j2];
      if (BIAS) v += bias[col];
      if (ACT == 1) v = 0.5f * v * (1.0f + erff(v * 0.70710678118654752f));
      C[(size_t)row * N + col] = v;
    }
  }
}

// ---------------- self-attention ----------------
// score[((i*B+b)*H+n)*S + j] = (AC+BD)*SCALE for j<=i else NEG
__global__ __launch_bounds__(256) void attn1_score_kernel(const float* __restrict__ heads,
                                                          const float* __restrict__ r_k,
                                                          const float* __restrict__ rw_bias,
                                                          const float* __restrict__ rr_bias,
                                                          float* __restrict__ score) {
  int i = blockIdx.x, b = blockIdx.y;
  __shared__ float q_rw[D_];
  __shared__ float q_rr[D_];
  const float* qrow = heads + ((size_t)(i * B_ + b)) * (3 * D_);
  for (int t = threadIdx.x; t < D_; t += 256) {
    float qv = qrow[t];
    q_rw[t] = qv + rw_bias[t];
    q_rr[t] = qv + rr_bias[t];
  }
  __syncthreads();
  for (int it = threadIdx.x; it < H_ * S_; it += 256) {
    int n = it >> 7;       // /S_
    int j = it & (S_ - 1);
    size_t sidx = (((size_t)i * B_ + b) * H_ + n) * S_ + j;
    if (j > i) { score[sidx] = NEGV; continue; }
    const float* krow = heads + ((size_t)(j * B_ + b)) * (3 * D_) + D_ + n * DH_;
    int jrel = S_ - 1 - i + j;  // rel_shift: BD[i,j] = pre[i, S-1-i+j]
    const float* rrow = r_k + (size_t)jrel * D_ + n * DH_;
    const float* qw = q_rw + n * DH_;
    const float* qr = q_rr + n * DH_;
    float ac = 0.f, bd = 0.f;
#pragma unroll 8
    for (int d = 0; d < DH_; ++d) {
      ac += qw[d] * krow[d];
      bd += qr[d] * rrow[d];
    }
    score[sidx] = (ac + bd) * SCALE_F;
  }
}

// generic in-place row softmax, one block per row
__global__ void softmax_kernel(float* __restrict__ data, int len) {
  __shared__ float sred[4];
  float* p = data + (size_t)blockIdx.x * len;
  float m = -3.4e38f;
  for (int t = threadIdx.x; t < len; t += blockDim.x) m = fmaxf(m, p[t]);
  m = block_reduce_max(m, sred);
  float s = 0.f;
  for (int t = threadIdx.x; t < len; t += blockDim.x) {
    float e = expf(p[t] - m);
    p[t] = e;
    s += e;
  }
  s = block_reduce_sum(s, sred);
  float inv = 1.0f / s;
  for (int t = threadIdx.x; t < len; t += blockDim.x) p[t] *= inv;
}

__global__ __launch_bounds__(256) void attn1_vec_kernel(const float* __restrict__ heads,
                                                        const float* __restrict__ prob,
                                                        float* __restrict__ vec) {
  int i = blockIdx.x, b = blockIdx.y;
  __shared__ float pr[H_ * S_];  // 2048 floats
  for (int t = threadIdx.x; t < H_ * S_; t += 256)
    pr[t] = prob[(((size_t)i * B_ + b) * H_) * S_ + t];
  __syncthreads();
  int jmax = i;
  for (int t = threadIdx.x; t < D_; t += 256) {
    int n = t >> 6, d = t & 63;
    const float* pn = pr + n * S_;
    float s = 0.f;
    for (int j = 0; j <= jmax; ++j)
      s += pn[j] * heads[((size_t)(j * B_ + b)) * (3 * D_) + 2 * D_ + n * DH_ + d];
    vec[((size_t)(i * B_ + b)) * D_ + t] = s;
  }
}

// ---------------- add + layernorm ----------------
__global__ __launch_bounds__(256) void addln_kernel(const float* __restrict__ a,
                                                    const float* __restrict__ c,
                                                    const float* __restrict__ g,
                                                    const float* __restrict__ bb,
                                                    float* __restrict__ out) {
  __shared__ float sred[4];
  int row = blockIdx.x;
  const float* pa = a + (size_t)row * D_;
  const float* pc = c + (size_t)row * D_;
  float vals[4];
  float s = 0.f;
#pragma unroll
  for (int it = 0; it < 4; ++it) {
    int idx = threadIdx.x + it * 256;
    float v = pa[idx] + pc[idx];
    vals[it] = v;
    s += v;
  }
  s = block_reduce_sum(s, sred);
  float mean = s * (1.0f / D_);
  float ss = 0.f;
#pragma unroll
  for (int it = 0; it < 4; ++it) {
    float dd = vals[it] - mean;
    ss += dd * dd;
  }
  ss = block_reduce_sum(ss, sred);
  float inv = rsqrtf(ss * (1.0f / D_) + 1e-5f);
#pragma unroll
  for (int it = 0; it < 4; ++it) {
    int idx = threadIdx.x + it * 256;
    out[(size_t)row * D_ + idx] = (vals[it] - mean) * inv * g[idx] + bb[idx];
  }
}

// ---------------- cross-attention ----------------
__global__ __launch_bounds__(256) void attn2_score_kernel(const float* __restrict__ q2,
                                                          const float* __restrict__ kv,
                                                          const float* __restrict__ mask,
                                                          float* __restrict__ score2) {
  int s = blockIdx.x, b = blockIdx.y;
  __shared__ float q[D_];
  for (int t = threadIdx.x; t < D_; t += 256) q[t] = q2[((size_t)(s * B_ + b)) * D_ + t];
  __syncthreads();
  for (int it = threadIdx.x; it < H_ * E_; it += 256) {
    int n = it >> 9;        // /E_
    int e = it & (E_ - 1);
    const float* krow = kv + ((size_t)(e * B_ + b)) * (2 * D_) + n * DH_;
    const float* qn = q + n * DH_;
    float acc = 0.f;
#pragma unroll 8
    for (int d = 0; d < DH_; ++d) acc += qn[d] * krow[d];
    score2[(((size_t)s * B_ + b) * H_ + n) * E_ + e] =
        acc * SCALE_F + (1.0f - mask[b * E_ + e]) * NEGV;
  }
}

__global__ __launch_bounds__(256) void attn2_vec_kernel(const float* __restrict__ kv,
                                                        const float* __restrict__ prob2,
                                                        float* __restrict__ vec2) {
  int s = blockIdx.x, b = blockIdx.y;
  __shared__ float pr[H_ * E_];  // 8192 floats = 32 KB
  for (int t = threadIdx.x; t < H_ * E_; t += 256)
    pr[t] = prob2[(((size_t)s * B_ + b) * H_) * E_ + t];
  __syncthreads();
  for (int t = threadIdx.x; t < D_; t += 256) {
    int n = t >> 6, d = t & 63;
    const float* pn = pr + n * E_;
    float acc = 0.f;
    for (int e = 0; e < E_; ++e)
      acc += pn[e] * kv[((size_t)(e * B_ + b)) * (2 * D_) + D_ + n * DH_ + d];
    vec2[((size_t)(s * B_ + b)) * D_ + t] = acc;
  }
}

// ---------------- heads: mode sigmoid ----------------
__global__ __launch_bounds__(256) void mode_kernel(const float* __restrict__ core,
                                                   const float* __restrict__ mode_w,
                                                   const float* __restrict__ mode_b,
                                                   float* __restrict__ mode_sig) {
  __shared__ float sred[4];
  int m = blockIdx.x;
  const float* a = core + (size_t)m * D_;
  float s = 0.f;
  for (int t = threadIdx.x; t < D_; t += 256) s += a[t] * mode_w[t];
  s = block_reduce_sum(s, sred);
  if (threadIdx.x == 0) mode_sig[m] = 1.0f / (1.0f + expf(-(s + mode_b[0])));
}

// ---------------- vocab softmax partials (tile max/sumexp, never materialize logits) --------
__global__ __launch_bounds__(256) void vocab_gemm_kernel(const float* __restrict__ A,
                                                         const float* __restrict__ W,
                                                         float* __restrict__ tmax,
                                                         float* __restrict__ tsum) {
  __shared__ float As[16][65];
  __shared__ float Ws[16][65];
  __shared__ float tile[64][65];
  int tid = threadIdx.x;
  int bn = blockIdx.x * 64;  // vocab
  int bm = blockIdx.y * 64;  // rows
  int tx = tid & 15, ty = tid >> 4;
  float acc[4][4] = {};
  int e = tid * 4;
  int r = e >> 4, kk = e & 15;
  for (int k0 = 0; k0 < D_; k0 += 16) {
    float4 av = *(const float4*)(A + (size_t)(bm + r) * D_ + k0 + kk);
    As[kk + 0][r] = av.x; As[kk + 1][r] = av.y; As[kk + 2][r] = av.z; As[kk + 3][r] = av.w;
    float4 wv = *(const float4*)(W + (size_t)(bn + r) * D_ + k0 + kk);
    Ws[kk + 0][r] = wv.x; Ws[kk + 1][r] = wv.y; Ws[kk + 2][r] = wv.z; Ws[kk + 3][r] = wv.w;
    __syncthreads();
#pragma unroll
    for (int k2 = 0; k2 < 16; ++k2) {
      float a0[4], b0[4];
#pragma unroll
      for (int i2 = 0; i2 < 4; ++i2) a0[i2] = As[k2][ty * 4 + i2];
#pragma unroll
      for (int j2 = 0; j2 < 4; ++j2) b0[j2] = Ws[k2][tx * 4 + j2];
#pragma unroll
      for (int i2 = 0; i2 < 4; ++i2)
#pragma unroll
        for (int j2 = 0; j2 < 4; ++j2) acc[i2][j2] += a0[i2] * b0[j2];
    }
    __syncthreads();
  }
#pragma unroll
  for (int i2 = 0; i2 < 4; ++i2)
#pragma unroll
    for (int j2 = 0; j2 < 4; ++j2) tile[ty * 4 + i2][tx * 4 + j2] = acc[i2][j2];
  __syncthreads();
  if (tid < 64) {
    float m = -3.4e38f;
#pragma unroll
    for (int c2 = 0; c2 < 64; ++c2) m = fmaxf(m, tile[tid][c2]);
    float ssum = 0.f;
#pragma unroll
    for (int c2 = 0; c2 < 64; ++c2) ssum += expf(tile[tid][c2] - m);
    tmax[(size_t)(bm + tid) * NT_ + blockIdx.x] = m;
    tsum[(size_t)(bm + tid) * NT_ + blockIdx.x] = ssum;
  }
}

__global__ __launch_bounds__(256) void vocab_combine_kernel(const float* __restrict__ tmax,
                                                            const float* __restrict__ tsum,
                                                            float* __restrict__ rmax,
                                                            float* __restrict__ rsum) {
  __shared__ float sred[4];
  int m = blockIdx.x;
  float mx = -3.4e38f;
  for (int t = threadIdx.x; t < NT_; t += 256) mx = fmaxf(mx, tmax[(size_t)m * NT_ + t]);
  mx = block_reduce_max(mx, sred);
  float s = 0.f;
  for (int t = threadIdx.x; t < NT_; t += 256)
    s += tsum[(size_t)m * NT_ + t] * expf(tmax[(size_t)m * NT_ + t] - mx);
  s = block_reduce_sum(s, sred);
  if (threadIdx.x == 0) { rmax[m] = mx; rsum[m] = s; }
}

__global__ __launch_bounds__(256) void tlogit_kernel(const float* __restrict__ outbuf,
                                                     const float* __restrict__ emb,
                                                     const int* __restrict__ tgt,
                                                     float* __restrict__ tl) {
  __shared__ float sred[4];
  int m = blockIdx.x;
  int s = m >> 3, b = m & 7;
  int t = tgt[b * S_ + s];
  const float* a = outbuf + (size_t)m * D_;
  const float* w = emb + (size_t)t * D_;
  float acc = 0.f;
  for (int i = threadIdx.x; i < D_; i += 256) acc += a[i] * w[i];
  acc = block_reduce_sum(acc, sred);
  if (threadIdx.x == 0) tl[m] = acc;
}

// ---------------- final: copy attention + loss ----------------
__global__ __launch_bounds__(256) void final_kernel(const float* __restrict__ copyh,
                                                    const float* __restrict__ enc,
                                                    const int* __restrict__ ids,
                                                    const float* __restrict__ mask,
                                                    const int* __restrict__ tgt,
                                                    const float* __restrict__ mode_sig,
                                                    const float* __restrict__ rmax,
                                                    const float* __restrict__ rsum,
                                                    const float* __restrict__ tlogit,
                                                    float* __restrict__ loss_acc) {
  __shared__ float ch[D_];
  __shared__ float lg[E_];
  __shared__ float sred[4];
  int s = blockIdx.x, b = blockIdx.y;
  int m = s * B_ + b;
  for (int t = threadIdx.x; t < D_; t += 256) ch[t] = copyh[(size_t)m * D_ + t];
  __syncthreads();
  for (int e = threadIdx.x; e < E_; e += 256) {
    const float* er = enc + ((size_t)b * E_ + e) * D_;
    float acc = 0.f;
    for (int d = 0; d < D_; ++d) acc += ch[d] * er[d];
    lg[e] = acc + (1.0f - mask[b * E_ + e]) * NEGV;
  }
  __syncthreads();
  float mx = -3.4e38f;
  for (int e = threadIdx.x; e < E_; e += 256) mx = fmaxf(mx, lg[e]);
  mx = block_reduce_max(mx, sred);
  int t = tgt[b * S_ + s];
  float ssum = 0.f, csum = 0.f;
  for (int e = threadIdx.x; e < E_; e += 256) {
    float ev = expf(lg[e] - mx);
    ssum += ev;
    if (ids[b * E_ + e] == t) csum += ev;
  }
  ssum = block_reduce_sum(ssum, sred);
  csum = block_reduce_sum(csum, sred);
  if (threadIdx.x == 0) {
    float copy_p = csum / ssum;
    float pv = expf(tlogit[m] - rmax[m]) / rsum[m];
    float msig = mode_sig[m];
    float predict = pv * msig + (1.0f - msig) * copy_p;
    float valid = (t != 0) ? 1.0f : 0.0f;
    atomicAdd(&loss_acc[0], -logf(predict + 1e-6f) * valid);
    atomicAdd(&loss_acc[1], valid);
  }
}

__global__ void writeout_kernel(const float* __restrict__ loss_acc, float* __restrict__ out) {
  if (threadIdx.x < B_) out[threadIdx.x] = loss_acc[0] / loss_acc[1];
}

// ---------------- host side ----------------
static void gemm(hipStream_t st, const float* A, const float* W, const float* bias, float* C,
                 int M, int N, int K, bool hasBias, int act) {
  dim3 grid(N / 64, M / 64);
  if (hasBias) {
    if (act == 1)
      gemm_kernel<true, 1><<<grid, 256, 0, st>>>(A, W, bias, C, M, N, K);
    else
      gemm_kernel<true, 0><<<grid, 256, 0, st>>>(A, W, bias, C, M, N, K);
  } else {
    gemm_kernel<false, 0><<<grid, 256, 0, st>>>(A, W, bias, C, M, N, K);
  }
}

extern "C" void kernel_launch(void* const* d_in, const int* in_sizes, int n_in,
                              void* d_out, int out_size, void* d_ws, size_t ws_size,
                              hipStream_t stream) {
  const int* input_ids = (const int*)d_in[0];
  const float* encoder_rep = (const float*)d_in[1];
  const float* input_mask = (const float*)d_in[2];
  const int* decode_input = (const int*)d_in[3];
  const int* decode_target = (const int*)d_in[4];
  const float* word_emb = (const float*)d_in[5];
  const float* qkv_w = (const float*)d_in[6];
  const float* r_w = (const float*)d_in[7];
  const float* o_w = (const float*)d_in[8];
  const float* kv_w = (const float*)d_in[9];
  const float* q_w = (const float*)d_in[10];
  const float* io_w = (const float*)d_in[11];
  const float* rr_bias = (const float*)d_in[12];
  const float* rw_bias = (const float*)d_in[13];
  const float* ln1_g = (const float*)d_in[14];
  const float* ln1_b = (const float*)d_in[15];
  const float* ln2_g = (const float*)d_in[16];
  const float* ln2_b = (const float*)d_in[17];
  const float* ffn_w1 = (const float*)d_in[18];
  const float* ffn_b1 = (const float*)d_in[19];
  const float* ffn_w2 = (const float*)d_in[20];
  const float* ffn_b2 = (const float*)d_in[21];
  const float* ln3_g = (const float*)d_in[22];
  const float* ln3_b = (const float*)d_in[23];
  const float* out_w = (const float*)d_in[24];
  const float* out_b = (const float*)d_in[25];
  const float* copy_w = (const float*)d_in[26];
  const float* copy_b = (const float*)d_in[27];
  const float* mode_w = (const float*)d_in[28];
  const float* mode_b = (const float*)d_in[29];
  float* out = (float*)d_out;
  float* ws = (float*)d_ws;

  size_t o = 0;
  float* f_r = ws + o;      o += (size_t)S_ * D_;
  float* f_rk = ws + o;     o += (size_t)S_ * D_;
  float* f_core = ws + o;   o += (size_t)M_ * D_;
  float* f_heads = ws + o;  o += (size_t)M_ * 3 * D_;
  float* f_score = ws + o;  o += (size_t)S_ * B_ * H_ * S_;
  float* f_vec = ws + o;    o += (size_t)M_ * D_;
  float* f_tmp = ws + o;    o += (size_t)M_ * D_;
  float* f_x = ws + o;      o += (size_t)M_ * D_;
  float* f_kv = ws + o;     o += (size_t)ME_ * 2 * D_;
  float* f_q2 = ws + o;     o += (size_t)M_ * D_;
  float* f_score2 = ws + o; o += (size_t)S_ * B_ * H_ * E_;
  float* f_y = ws + o;      o += (size_t)M_ * D_;
  float* f_ffnh = ws + o;   o += (size_t)M_ * FF_;
  float* f_out = ws + o;    o += (size_t)M_ * D_;
  float* f_copyh = ws + o;  o += (size_t)M_ * D_;
  float* f_enc = ws + o;    o += (size_t)ME_ * D_;
  float* f_mode = ws + o;   o += M_;
  float* f_tmax = ws + o;   o += (size_t)M_ * NT_;
  float* f_tsum = ws + o;   o += (size_t)M_ * NT_;
  float* f_rmax = ws + o;   o += M_;
  float* f_rsum = ws + o;   o += M_;
  float* f_tlogit = ws + o; o += M_;
  float* f_loss = ws + o;   o += 8;

  pos_emb_kernel<<<(S_ * D_ + 255) / 256, 256, 0, stream>>>(f_r);
  embed_kernel<<<(M_ * D_) / 256, 256, 0, stream>>>(decode_input, word_emb, f_core);
  enc_t_kernel<<<(ME_ * D_) / 256, 256, 0, stream>>>(encoder_rep, f_enc);

  for (int l = 0; l < L_; ++l) {
    // self-attention
    gemm(stream, f_core, qkv_w + (size_t)l * 3 * D_ * D_, nullptr, f_heads, M_, 3 * D_, D_, false, 0);
    gemm(stream, f_r, r_w + (size_t)l * D_ * D_, nullptr, f_rk, S_, D_, D_, false, 0);
    attn1_score_kernel<<<dim3(S_, B_), 256, 0, stream>>>(f_heads, f_rk, rw_bias + (size_t)l * D_,
                                                         rr_bias + (size_t)l * D_, f_score);
    softmax_kernel<<<S_ * B_ * H_, 128, 0, stream>>>(f_score, S_);
    attn1_vec_kernel<<<dim3(S_, B_), 256, 0, stream>>>(f_heads, f_score, f_vec);
    gemm(stream, f_vec, o_w + (size_t)l * D_ * D_, nullptr, f_tmp, M_, D_, D_, false, 0);
    addln_kernel<<<M_, 256, 0, stream>>>(f_core, f_tmp, ln1_g + (size_t)l * D_, ln1_b + (size_t)l * D_, f_x);

    // cross-attention
    gemm(stream, f_enc, kv_w + (size_t)l * 2 * D_ * D_, nullptr, f_kv, ME_, 2 * D_, D_, false, 0);
    gemm(stream, f_x, q_w + (size_t)l * D_ * D_, nullptr, f_q2, M_, D_, D_, false, 0);
    attn2_score_kernel<<<dim3(S_, B_), 256, 0, stream>>>(f_q2, f_kv, input_mask, f_score2);
    softmax_kernel<<<S_ * B_ * H_, 256, 0, stream>>>(f_score2, E_);
    attn2_vec_kernel<<<dim3(S_, B_), 256, 0, stream>>>(f_kv, f_score2, f_vec);
    gemm(stream, f_vec, io_w + (size_t)l * D_ * D_, nullptr, f_tmp, M_, D_, D_, false, 0);
    addln_kernel<<<M_, 256, 0, stream>>>(f_x, f_tmp, ln2_g + (size_t)l * D_, ln2_b + (size_t)l * D_, f_y);

    // FFN
    gemm(stream, f_y, ffn_w1 + (size_t)l * FF_ * D_, ffn_b1 + (size_t)l * FF_, f_ffnh, M_, FF_, D_, true, 1);
    gemm(stream, f_ffnh, ffn_w2 + (size_t)l * D_ * FF_, ffn_b2 + (size_t)l * D_, f_tmp, M_, D_, FF_, true, 0);
    addln_kernel<<<M_, 256, 0, stream>>>(f_y, f_tmp, ln3_g + (size_t)l * D_, ln3_b + (size_t)l * D_, f_core);
  }

  // output heads
  gemm(stream, f_core, out_w, out_b, f_out, M_, D_, D_, true, 0);
  gemm(stream, f_core, copy_w, copy_b, f_copyh, M_, D_, D_, true, 0);
  mode_kernel<<<M_, 256, 0, stream>>>(f_core, mode_w, mode_b, f_mode);

  vocab_gemm_kernel<<<dim3(V_ / 64, M_ / 64), 256, 0, stream>>>(f_out, word_emb, f_tmax, f_tsum);
  vocab_combine_kernel<<<M_, 256, 0, stream>>>(f_tmax, f_tsum, f_rmax, f_rsum);
  tlogit_kernel<<<M_, 256, 0, stream>>>(f_out, word_emb, decode_target, f_tlogit);

  hipMemsetAsync(f_loss, 0, 2 * sizeof(float), stream);
  final_kernel<<<dim3(S_, B_), 256, 0, stream>>>(f_copyh, encoder_rep, input_ids, input_mask,
                                                 decode_target, f_mode, f_rmax, f_rsum,
                                                 f_tlogit, f_loss);
  writeout_kernel<<<1, 64, 0, stream>>>(f_loss, out);
}

// Round 2
// 2383.146 us; speedup vs baseline: 4.0439x; 4.0439x over previous
//
#include <hip/hip_runtime.h>
#include <math.h>

#define B_ 8
#define S_ 128
#define E_ 512
#define D_ 1024
#define H_ 16
#define L_ 4
#define V_ 32000
#define DH_ 64
#define FF_ 4096
#define M_ 1024      // S_*B_ rows, row = s*B_+b
#define ME_ 4096     // E_*B_ rows, row = e*B_+b
#define SCALE_F 0.125f
#define NEGV (-1e30f)

typedef __attribute__((ext_vector_type(8))) short short8;
typedef __attribute__((ext_vector_type(4))) float f32x4;

// ---------------- helpers ----------------
__device__ __forceinline__ float bf2f(ushort u) {
  union { unsigned int u32; float f; } v; v.u32 = ((unsigned int)u) << 16; return v.f;
}
__device__ __forceinline__ ushort f2bf(float x) {
  union { float f; unsigned int u; } v; v.f = x;
  unsigned int r = v.u + 0x7fff + ((v.u >> 16) & 1);
  return (ushort)(r >> 16);
}
__device__ __forceinline__ void gl_lds16(const ushort* g, ushort* l) {
  __builtin_amdgcn_global_load_lds((const __attribute__((address_space(1))) void*)g,
                                   (__attribute__((address_space(3))) void*)l, 16, 0, 0);
}

__device__ __forceinline__ float warp_reduce_sum(float v) {
#pragma unroll
  for (int o = 32; o > 0; o >>= 1) v += __shfl_down(v, o);
  return v;
}
__device__ __forceinline__ float warp_reduce_max(float v) {
#pragma unroll
  for (int o = 32; o > 0; o >>= 1) v = fmaxf(v, __shfl_down(v, o));
  return v;
}
__device__ __forceinline__ float block_reduce_sum(float v, float* sred) {
  v = warp_reduce_sum(v);
  __syncthreads();
  if ((threadIdx.x & 63) == 0) sred[threadIdx.x >> 6] = v;
  __syncthreads();
  float s = 0.0f;
  int nw = blockDim.x >> 6;
  for (int w = 0; w < nw; ++w) s += sred[w];
  return s;
}
__device__ __forceinline__ float block_reduce_max(float v, float* sred) {
  v = warp_reduce_max(v);
  __syncthreads();
  if ((threadIdx.x & 63) == 0) sred[threadIdx.x >> 6] = v;
  __syncthreads();
  float s = -3.4e38f;
  int nw = blockDim.x >> 6;
  for (int w = 0; w < nw; ++w) s = fmaxf(s, sred[w]);
  return s;
}

// ---------------- cast kernels ----------------
__global__ __launch_bounds__(256) void castf_kernel(const float* __restrict__ in,
                                                    ushort* __restrict__ out, int n4) {
  int t = blockIdx.x * 256 + threadIdx.x;
  if (t >= n4) return;
  float4 v = ((const float4*)in)[t];
  ushort4 o;
  o.x = f2bf(v.x); o.y = f2bf(v.y); o.z = f2bf(v.z); o.w = f2bf(v.w);
  ((ushort4*)out)[t] = o;
}

// encoder_rep [b,e,d] -> encT_bf rows (e*B+b)
__global__ __launch_bounds__(256) void enct_kernel(const float* __restrict__ enc,
                                                   ushort* __restrict__ encT) {
  int t = blockIdx.x * 256 + threadIdx.x;  // ME_*D_
  if (t >= ME_ * D_) return;
  int d = t & (D_ - 1);
  int row = t >> 10;
  int e = row >> 3, b = row & 7;
  encT[t] = f2bf(enc[((size_t)b * E_ + e) * D_ + d]);
}

__global__ __launch_bounds__(256) void pos_emb_kernel(ushort* __restrict__ r) {
  int t = blockIdx.x * 256 + threadIdx.x;
  if (t >= S_ * D_) return;
  int i = t / D_, j = t % D_;
  float pos = (float)(S_ - 1 - i);
  int jj = (j < D_ / 2) ? j : (j - D_ / 2);
  float invf = powf(10000.0f, -(float)(2 * jj) / (float)D_);
  float a = pos * invf;
  r[t] = f2bf((j < D_ / 2) ? sinf(a) : cosf(a));
}

__global__ __launch_bounds__(256) void embed_kernel(const int* __restrict__ ids,
                                                    const float* __restrict__ emb,
                                                    float* __restrict__ core,
                                                    ushort* __restrict__ core_bf) {
  int t = blockIdx.x * 256 + threadIdx.x;
  if (t >= M_ * D_) return;
  int d = t & (D_ - 1);
  int row = t >> 10;
  int s = row >> 3, b = row & 7;
  float v = emb[(size_t)ids[b * S_ + s] * D_ + d];
  core[t] = v;
  core_bf[t] = f2bf(v);
}

// ---------------- bf16 MFMA GEMM, 128x128 tile, strided-batched ----------------
// C[m,n] = sum_k A[m,k]*B[n,k]  (B transposed form). EPI: 0 f32, 1 bf16,
// 2 f32+bias, 3 bf16+bias, 4 bf16+bias+gelu
template <int EPI>
__global__ __launch_bounds__(256) void gemm_w_kernel(
    const ushort* __restrict__ A, const ushort* __restrict__ Bm,
    const float* __restrict__ bias, void* __restrict__ Cv,
    int M, int N, int K,
    long long Arow, long long Abatch, long long Brow, long long Bbatch,
    long long Crow, long long Cbatch, int bmodB) {
  __shared__ ushort lA[128 * 32];
  __shared__ ushort lB[128 * 32];
  int tid = threadIdx.x;
  int bz = blockIdx.z;
  const ushort* Ab = A + (size_t)bz * Abatch;
  const ushort* Bb = Bm + (size_t)(bmodB ? (bz % bmodB) : bz) * Bbatch;
  int bm = blockIdx.y * 128, bn = blockIdx.x * 128;
  int lane = tid & 63, wave = tid >> 6;
  int wrow = (wave >> 1) * 64, wcol = (wave & 1) * 64;
  int quad = lane >> 4, l16 = lane & 15;
  f32x4 acc[4][4];
#pragma unroll
  for (int i = 0; i < 4; ++i)
#pragma unroll
    for (int j = 0; j < 4; ++j) { acc[i][j][0] = 0.f; acc[i][j][1] = 0.f; acc[i][j][2] = 0.f; acc[i][j][3] = 0.f; }
  int r0 = tid >> 2, c0 = (tid & 3) * 8;
  int r1 = (tid + 256) >> 2;
  for (int k0 = 0; k0 < K; k0 += 32) {
    __syncthreads();
    gl_lds16(Ab + (size_t)(bm + r0) * Arow + k0 + c0, &lA[(size_t)tid * 8]);
    gl_lds16(Ab + (size_t)(bm + r1) * Arow + k0 + c0, &lA[(size_t)(256 + tid) * 8]);
    gl_lds16(Bb + (size_t)(bn + r0) * Brow + k0 + c0, &lB[(size_t)tid * 8]);
    gl_lds16(Bb + (size_t)(bn + r1) * Brow + k0 + c0, &lB[(size_t)(256 + tid) * 8]);
    __syncthreads();
    short8 af[4], bfr[4];
#pragma unroll
    for (int mi = 0; mi < 4; ++mi)
      af[mi] = *(const short8*)&lA[(size_t)(wrow + mi * 16 + l16) * 32 + quad * 8];
#pragma unroll
    for (int ni = 0; ni < 4; ++ni)
      bfr[ni] = *(const short8*)&lB[(size_t)(wcol + ni * 16 + l16) * 32 + quad * 8];
#pragma unroll
    for (int mi = 0; mi < 4; ++mi)
#pragma unroll
      for (int ni = 0; ni < 4; ++ni)
        acc[mi][ni] = __builtin_amdgcn_mfma_f32_16x16x32_bf16(af[mi], bfr[ni], acc[mi][ni], 0, 0, 0);
  }
  // epilogue
#pragma unroll
  for (int mi = 0; mi < 4; ++mi) {
    int row0 = bm + wrow + mi * 16 + quad * 4;
#pragma unroll
    for (int ni = 0; ni < 4; ++ni) {
      int col = bn + wcol + ni * 16 + l16;
      float bv = 0.f;
      if (EPI >= 2) bv = bias[col];
#pragma unroll
      for (int r = 0; r < 4; ++r) {
        float v = acc[mi][ni][r] + bv;
        if (EPI == 4) v = 0.5f * v * (1.0f + erff(v * 0.70710678118654752f));
        size_t ci = (size_t)bz * Cbatch + (size_t)(row0 + r) * Crow + col;
        if (EPI == 0 || EPI == 2) ((float*)Cv)[ci] = v;
        else ((ushort*)Cv)[ci] = f2bf(v);
      }
    }
  }
}

// narrow variant: tile 128x64, 128 threads (2 waves stacked on rows), f32 out
__global__ __launch_bounds__(128) void gemm_n_kernel(
    const ushort* __restrict__ A, const ushort* __restrict__ Bm,
    float* __restrict__ C, int M, int K,
    long long Arow, long long Abatch, long long Brow, long long Bbatch,
    long long Crow, long long Cbatch) {
  __shared__ ushort lA[128 * 32];
  __shared__ ushort lB[64 * 32];
  int tid = threadIdx.x;
  int bz = blockIdx.z;
  const ushort* Ab = A + (size_t)bz * Abatch;
  const ushort* Bb = Bm + (size_t)bz * Bbatch;
  int bm = blockIdx.y * 128;
  int lane = tid & 63, wave = tid >> 6;
  int wrow = wave * 64;
  int quad = lane >> 4, l16 = lane & 15;
  f32x4 acc[4][4];
#pragma unroll
  for (int i = 0; i < 4; ++i)
#pragma unroll
    for (int j = 0; j < 4; ++j) { acc[i][j][0] = 0.f; acc[i][j][1] = 0.f; acc[i][j][2] = 0.f; acc[i][j][3] = 0.f; }
  for (int k0 = 0; k0 < K; k0 += 32) {
    __syncthreads();
#pragma unroll
    for (int c = 0; c < 4; ++c) {
      int idx = c * 128 + tid;
      gl_lds16(Ab + (size_t)(bm + (idx >> 2)) * Arow + k0 + (idx & 3) * 8, &lA[(size_t)idx * 8]);
    }
#pragma unroll
    for (int c = 0; c < 2; ++c) {
      int idx = c * 128 + tid;
      gl_lds16(Bb + (size_t)(idx >> 2) * Brow + k0 + (idx & 3) * 8, &lB[(size_t)idx * 8]);
    }
    __syncthreads();
    short8 af[4], bfr[4];
#pragma unroll
    for (int mi = 0; mi < 4; ++mi)
      af[mi] = *(const short8*)&lA[(size_t)(wrow + mi * 16 + l16) * 32 + quad * 8];
#pragma unroll
    for (int ni = 0; ni < 4; ++ni)
      bfr[ni] = *(const short8*)&lB[(size_t)(ni * 16 + l16) * 32 + quad * 8];
#pragma unroll
    for (int mi = 0; mi < 4; ++mi)
#pragma unroll
      for (int ni = 0; ni < 4; ++ni)
        acc[mi][ni] = __builtin_amdgcn_mfma_f32_16x16x32_bf16(af[mi], bfr[ni], acc[mi][ni], 0, 0, 0);
  }
#pragma unroll
  for (int mi = 0; mi < 4; ++mi) {
    int row0 = bm + wrow + mi * 16 + quad * 4;
#pragma unroll
    for (int ni = 0; ni < 4; ++ni) {
      int col = ni * 16 + l16;
#pragma unroll
      for (int r = 0; r < 4; ++r)
        C[(size_t)bz * Cbatch + (size_t)(row0 + r) * Crow + col] = acc[mi][ni][r];
    }
  }
}

// ---------------- attention glue ----------------
// heads_bf [(s*B+b), 3D] -> qrw/qrr/k in [b,n,s,d] bf16
__global__ __launch_bounds__(256) void prep1_kernel(const ushort* __restrict__ heads,
                                                    const float* __restrict__ rw,
                                                    const float* __restrict__ rr,
                                                    ushort* __restrict__ qrw,
                                                    ushort* __restrict__ qrr,
                                                    ushort* __restrict__ kb) {
  int t = blockIdx.x * 256 + threadIdx.x;  // B*H*S*64 = 1M
  if (t >= B_ * H_ * S_ * DH_) return;
  int d = t & 63;
  int s = (t >> 6) & 127;
  int n = (t >> 13) & 15;
  int b = t >> 17;
  size_t src = ((size_t)(s * 8 + b)) * 3072 + n * 64 + d;
  float q = bf2f(heads[src]);
  qrw[t] = f2bf(q + rw[n * 64 + d]);
  qrr[t] = f2bf(q + rr[n * 64 + d]);
  kb[t] = heads[src + 1024];
}

// transpose V slice to [b,n,d,e] layout; grid (128 bn, nE/128)
__global__ __launch_bounds__(256) void vtrans_kernel(const ushort* __restrict__ src,
                                                     ushort* __restrict__ dst,
                                                     int rowLen, int vOff, int nE) {
  __shared__ ushort lds[64][130];
  int bn = blockIdx.x, b = bn >> 4, n = bn & 15;
  int e0 = blockIdx.y * 128;
  for (int idx = threadIdx.x; idx < 128 * 64; idx += 256) {
    int el = idx >> 6, d = idx & 63;
    lds[d][el] = src[((size_t)((e0 + el) * 8 + b)) * rowLen + vOff + n * 64 + d];
  }
  __syncthreads();
  for (int idx = threadIdx.x; idx < 128 * 64; idx += 256) {
    int d = idx >> 7, el = idx & 127;
    dst[((size_t)bn * 64 + d) * nE + e0 + el] = lds[d][el];
  }
}

// rows (s*B+b) layout -> [b,n,s',d]; s' count = 1<<sshift
__global__ __launch_bounds__(256) void scat_kernel(const ushort* __restrict__ in,
                                                   ushort* __restrict__ out,
                                                   int sshift, int rowLen, int colOff, int total) {
  int t = blockIdx.x * 256 + threadIdx.x;
  if (t >= total) return;
  int d = t & 63;
  int s = (t >> 6) & ((1 << sshift) - 1);
  int n = (t >> (6 + sshift)) & 15;
  int b = t >> (10 + sshift);
  out[t] = in[((size_t)(s * 8 + b)) * rowLen + colOff + n * 64 + d];
}

// rkproj_bf [s,1024] -> rk_bf [n,s,d]
__global__ __launch_bounds__(256) void rkprep_kernel(const ushort* __restrict__ in,
                                                     ushort* __restrict__ out) {
  int t = blockIdx.x * 256 + threadIdx.x;  // H*S*64
  if (t >= H_ * S_ * DH_) return;
  int d = t & 63;
  int s = (t >> 6) & 127;
  int n = t >> 13;
  out[t] = in[(size_t)s * 1024 + n * 64 + d];
}

// vec f32 [b,n,s,d] -> bf16 rows (s*B+b)[n*64+d]
__global__ __launch_bounds__(256) void repack_kernel(const float* __restrict__ vec,
                                                     ushort* __restrict__ out) {
  int t = blockIdx.x * 256 + threadIdx.x;  // 1M
  if (t >= M_ * D_) return;
  int d = t & 63;
  int n = (t >> 6) & 15;
  int b = (t >> 10) & 7;
  int s = t >> 13;
  out[t] = f2bf(vec[(((size_t)(b * 16 + n)) * 128 + s) * 64 + d]);
}

// softmax over j for score1 with rel-shift + causal; 128 threads = row
__global__ __launch_bounds__(128) void softmax1_kernel(const float* __restrict__ AC,
                                                       const float* __restrict__ BD,
                                                       ushort* __restrict__ prob) {
  __shared__ float sred[4];
  int bn = blockIdx.x >> 7, i = blockIdx.x & 127, j = threadIdx.x;
  size_t base = (size_t)bn * 16384 + (size_t)i * 128;
  float val = -3.4e38f;
  if (j <= i) val = (AC[base + j] + BD[base + (127 - i + j)]) * SCALE_F;
  float m = block_reduce_max(val, sred);
  float e = expf(val - m);
  float ssum = block_reduce_sum(e, sred);
  prob[base + j] = f2bf(e / ssum);
}

// softmax over e for score2 with input mask; 256 threads, len 512
__global__ __launch_bounds__(256) void softmax2_kernel(const float* __restrict__ sc2,
                                                       const float* __restrict__ mask,
                                                       ushort* __restrict__ prob2) {
  __shared__ float sred[4];
  int bn = blockIdx.x >> 7, s = blockIdx.x & 127;
  int b = bn >> 4;
  size_t base = (size_t)bn * 65536 + (size_t)s * 512;
  float v[2];
  float mx = -3.4e38f;
#pragma unroll
  for (int it = 0; it < 2; ++it) {
    int e = threadIdx.x + it * 256;
    float raw = sc2[base + e] * SCALE_F + (1.0f - mask[b * E_ + e]) * NEGV;
    v[it] = raw;
    mx = fmaxf(mx, raw);
  }
  mx = block_reduce_max(mx, sred);
  float ssum = 0.f;
  float ev[2];
#pragma unroll
  for (int it = 0; it < 2; ++it) { ev[it] = expf(v[it] - mx); ssum += ev[it]; }
  ssum = block_reduce_sum(ssum, sred);
  float inv = 1.0f / ssum;
#pragma unroll
  for (int it = 0; it < 2; ++it) {
    int e = threadIdx.x + it * 256;
    prob2[base + e] = f2bf(ev[it] * inv);
  }
}

// add + layernorm, emits fp32 and bf16
__global__ __launch_bounds__(256) void addln_kernel(const float* __restrict__ a,
                                                    const float* __restrict__ c,
                                                    const float* __restrict__ g,
                                                    const float* __restrict__ bb,
                                                    float* __restrict__ out,
                                                    ushort* __restrict__ out_bf) {
  __shared__ float sred[4];
  int row = blockIdx.x;
  const float* pa = a + (size_t)row * D_;
  const float* pc = c + (size_t)row * D_;
  float vals[4];
  float s = 0.f;
#pragma unroll
  for (int it = 0; it < 4; ++it) {
    int idx = threadIdx.x + it * 256;
    float v = pa[idx] + pc[idx];
    vals[it] = v;
    s += v;
  }
  s = block_reduce_sum(s, sred);
  float mean = s * (1.0f / D_);
  float ss = 0.f;
#pragma unroll
  for (int it = 0; it < 4; ++it) {
    float dd = vals[it] - mean;
    ss += dd * dd;
  }
  ss = block_reduce_sum(ss, sred);
  float inv = rsqrtf(ss * (1.0f / D_) + 1e-5f);
#pragma unroll
  for (int it = 0; it < 4; ++it) {
    int idx = threadIdx.x + it * 256;
    float r = (vals[it] - mean) * inv * g[idx] + bb[idx];
    out[(size_t)row * D_ + idx] = r;
    out_bf[(size_t)row * D_ + idx] = f2bf(r);
  }
}

__global__ __launch_bounds__(256) void mode_kernel(const float* __restrict__ core,
                                                   const float* __restrict__ mode_w,
                                                   const float* __restrict__ mode_b,
                                                   float* __restrict__ mode_sig) {
  __shared__ float sred[4];
  int m = blockIdx.x;
  const float* a = core + (size_t)m * D_;
  float s = 0.f;
  for (int t = threadIdx.x; t < D_; t += 256) s += a[t] * mode_w[t];
  s = block_reduce_sum(s, sred);
  if (threadIdx.x == 0) mode_sig[m] = 1.0f / (1.0f + expf(-(s + mode_b[0])));
}

// per-row softmax stats over bf16 logits + target prob
__global__ __launch_bounds__(256) void vocabstats_kernel(const ushort* __restrict__ logits,
                                                         const int* __restrict__ tgt,
                                                         float* __restrict__ pv) {
  __shared__ float sred[4];
  int m = blockIdx.x;
  int s = m >> 3, b = m & 7;
  const ushort* row = logits + (size_t)m * V_;
  float mx = -3.4e38f;
  for (int i = threadIdx.x; i < V_; i += 256) mx = fmaxf(mx, bf2f(row[i]));
  mx = block_reduce_max(mx, sred);
  float sm = 0.f;
  for (int i = threadIdx.x; i < V_; i += 256) sm += expf(bf2f(row[i]) - mx);
  sm = block_reduce_sum(sm, sred);
  if (threadIdx.x == 0) {
    int tg = tgt[b * S_ + s];
    pv[m] = expf(bf2f(row[tg]) - mx) / sm;
  }
}

// copy-attention softmax + gather + loss
__global__ __launch_bounds__(256) void final_kernel(const float* __restrict__ lg,
                                                    const int* __restrict__ ids,
                                                    const float* __restrict__ mask,
                                                    const int* __restrict__ tgt,
                                                    const float* __restrict__ mode_sig,
                                                    const float* __restrict__ pv,
                                                    float* __restrict__ loss_acc) {
  __shared__ float sred[4];
  int s = blockIdx.x, b = blockIdx.y;
  int m = s * B_ + b;
  size_t base = (size_t)(b * S_ + s) * E_;
  int tg = tgt[b * S_ + s];
  float lv[2];
  float mx = -3.4e38f;
#pragma unroll
  for (int it = 0; it < 2; ++it) {
    int e = threadIdx.x + it * 256;
    float raw = lg[base + e] + (1.0f - mask[b * E_ + e]) * NEGV;
    lv[it] = raw;
    mx = fmaxf(mx, raw);
  }
  mx = block_reduce_max(mx, sred);
  float ssum = 0.f, csum = 0.f;
#pragma unroll
  for (int it = 0; it < 2; ++it) {
    int e = threadIdx.x + it * 256;
    float ev = expf(lv[it] - mx);
    ssum += ev;
    if (ids[b * E_ + e] == tg) csum += ev;
  }
  ssum = block_reduce_sum(ssum, sred);
  csum = block_reduce_sum(csum, sred);
  if (threadIdx.x == 0) {
    float copy_p = csum / ssum;
    float msig = mode_sig[m];
    float predict = pv[m] * msig + (1.0f - msig) * copy_p;
    float valid = (tg != 0) ? 1.0f : 0.0f;
    atomicAdd(&loss_acc[0], -logf(predict + 1e-6f) * valid);
    atomicAdd(&loss_acc[1], valid);
  }
}

__global__ void writeout_kernel(const float* __restrict__ loss_acc, float* __restrict__ out) {
  if (threadIdx.x < B_) out[threadIdx.x] = loss_acc[0] / loss_acc[1];
}

// ---------------- host ----------------
static void gw(hipStream_t st, int epi, const ushort* A, const ushort* B, const float* bias,
               void* C, int M, int N, int K,
               long long Ar, long long Ab, long long Br, long long Bb,
               long long Cr, long long Cb, int nb, int bmod) {
  dim3 g(N / 128, M / 128, nb);
  switch (epi) {
    case 0: gemm_w_kernel<0><<<g, 256, 0, st>>>(A, B, bias, C, M, N, K, Ar, Ab, Br, Bb, Cr, Cb, bmod); break;
    case 1: gemm_w_kernel<1><<<g, 256, 0, st>>>(A, B, bias, C, M, N, K, Ar, Ab, Br, Bb, Cr, Cb, bmod); break;
    case 2: gemm_w_kernel<2><<<g, 256, 0, st>>>(A, B, bias, C, M, N, K, Ar, Ab, Br, Bb, Cr, Cb, bmod); break;
    case 3: gemm_w_kernel<3><<<g, 256, 0, st>>>(A, B, bias, C, M, N, K, Ar, Ab, Br, Bb, Cr, Cb, bmod); break;
    case 4: gemm_w_kernel<4><<<g, 256, 0, st>>>(A, B, bias, C, M, N, K, Ar, Ab, Br, Bb, Cr, Cb, bmod); break;
  }
}
static void gn(hipStream_t st, const ushort* A, const ushort* B, float* C, int M, int K,
               long long Ar, long long Ab, long long Br, long long Bb,
               long long Cr, long long Cb, int nb) {
  dim3 g(1, M / 128, nb);
  gemm_n_kernel<<<g, 128, 0, st>>>(A, B, C, M, K, Ar, Ab, Br, Bb, Cr, Cb);
}
static void castTo(hipStream_t st, const float* src, ushort* dst, size_t count) {
  int n4 = (int)(count / 4);
  castf_kernel<<<(n4 + 255) / 256, 256, 0, st>>>(src, dst, n4);
}

extern "C" void kernel_launch(void* const* d_in, const int* in_sizes, int n_in,
                              void* d_out, int out_size, void* d_ws, size_t ws_size,
                              hipStream_t stream) {
  const int* input_ids = (const int*)d_in[0];
  const float* encoder_rep = (const float*)d_in[1];
  const float* input_mask = (const float*)d_in[2];
  const int* decode_input = (const int*)d_in[3];
  const int* decode_target = (const int*)d_in[4];
  const float* word_emb = (const float*)d_in[5];
  const float* qkv_w = (const float*)d_in[6];
  const float* r_w = (const float*)d_in[7];
  const float* o_w = (const float*)d_in[8];
  const float* kv_w = (const float*)d_in[9];
  const float* q_w = (const float*)d_in[10];
  const float* io_w = (const float*)d_in[11];
  const float* rr_bias = (const float*)d_in[12];
  const float* rw_bias = (const float*)d_in[13];
  const float* ln1_g = (const float*)d_in[14];
  const float* ln1_b = (const float*)d_in[15];
  const float* ln2_g = (const float*)d_in[16];
  const float* ln2_b = (const float*)d_in[17];
  const float* ffn_w1 = (const float*)d_in[18];
  const float* ffn_b1 = (const float*)d_in[19];
  const float* ffn_w2 = (const float*)d_in[20];
  const float* ffn_b2 = (const float*)d_in[21];
  const float* ln3_g = (const float*)d_in[22];
  const float* ln3_b = (const float*)d_in[23];
  const float* out_w = (const float*)d_in[24];
  const float* out_b = (const float*)d_in[25];
  const float* copy_w = (const float*)d_in[26];
  const float* copy_b = (const float*)d_in[27];
  const float* mode_w = (const float*)d_in[28];
  const float* mode_b = (const float*)d_in[29];
  float* out = (float*)d_out;

  char* base = (char*)d_ws;
  size_t off = 0;
  auto alloc = [&](size_t bytes) -> void* {
    void* p = base + off;
    off = (off + bytes + 255) & ~(size_t)255;
    return p;
  };

  // per-layer reused weight buffers (bf16)
  ushort* wl_qkv = (ushort*)alloc((size_t)3 * D_ * D_ * 2);
  ushort* wl_r = (ushort*)alloc((size_t)D_ * D_ * 2);
  ushort* wl_o = (ushort*)alloc((size_t)D_ * D_ * 2);
  ushort* wl_kv = (ushort*)alloc((size_t)2 * D_ * D_ * 2);
  ushort* wl_q = (ushort*)alloc((size_t)D_ * D_ * 2);
  ushort* wl_io = (ushort*)alloc((size_t)D_ * D_ * 2);
  ushort* wl_f1 = (ushort*)alloc((size_t)FF_ * D_ * 2);
  ushort* wl_f2 = (ushort*)alloc((size_t)FF_ * D_ * 2);
  ushort* w_emb = (ushort*)alloc((size_t)V_ * D_ * 2);
  ushort* w_out = (ushort*)alloc((size_t)D_ * D_ * 2);
  ushort* w_cp = (ushort*)alloc((size_t)D_ * D_ * 2);
  ushort* enc_bf = (ushort*)alloc((size_t)ME_ * D_ * 2);
  ushort* encT_bf = (ushort*)alloc((size_t)ME_ * D_ * 2);
  // activations
  ushort* r_bf = (ushort*)alloc((size_t)S_ * D_ * 2);
  ushort* rkproj_bf = (ushort*)alloc((size_t)S_ * D_ * 2);
  ushort* rk_bf = (ushort*)alloc((size_t)S_ * D_ * 2);
  float* f_core = (float*)alloc((size_t)M_ * D_ * 4);
  ushort* core_bf = (ushort*)alloc((size_t)M_ * D_ * 2);
  ushort* heads_bf = (ushort*)alloc((size_t)M_ * 3 * D_ * 2);
  ushort* qrw_bf = (ushort*)alloc((size_t)M_ * D_ * 2);
  ushort* qrr_bf = (ushort*)alloc((size_t)M_ * D_ * 2);
  ushort* k_bf = (ushort*)alloc((size_t)M_ * D_ * 2);
  ushort* vT_bf = (ushort*)alloc((size_t)M_ * D_ * 2);
  float* f_sc2 = (float*)alloc((size_t)B_ * H_ * S_ * E_ * 4);  // also hosts AC/BD
  float* f_AC = f_sc2;
  float* f_BD = f_sc2 + (size_t)B_ * H_ * S_ * S_;
  ushort* prob_bf = (ushort*)alloc((size_t)B_ * H_ * S_ * S_ * 2);
  float* f_vec = (float*)alloc((size_t)M_ * D_ * 4);
  ushort* attnA_bf = (ushort*)alloc((size_t)M_ * D_ * 2);
  float* f_tmp = (float*)alloc((size_t)M_ * D_ * 4);
  float* f_x = (float*)alloc((size_t)M_ * D_ * 4);
  ushort* x_bf = (ushort*)alloc((size_t)M_ * D_ * 2);
  float* f_y = (float*)alloc((size_t)M_ * D_ * 4);
  ushort* y_bf = (ushort*)alloc((size_t)M_ * D_ * 2);
  ushort* kvproj_bf = (ushort*)alloc((size_t)ME_ * 2 * D_ * 2);
  ushort* qproj_bf = (ushort*)alloc((size_t)M_ * D_ * 2);
  ushort* q2_bf = (ushort*)alloc((size_t)M_ * D_ * 2);
  ushort* k2_bf = (ushort*)alloc((size_t)B_ * H_ * E_ * DH_ * 2);
  ushort* v2T_bf = (ushort*)alloc((size_t)B_ * H_ * E_ * DH_ * 2);
  ushort* prob2_bf = (ushort*)alloc((size_t)B_ * H_ * S_ * E_ * 2);
  ushort* ffnh_bf = (ushort*)alloc((size_t)M_ * FF_ * 2);
  ushort* fout_bf = (ushort*)alloc((size_t)M_ * D_ * 2);
  ushort* copyh_bf = (ushort*)alloc((size_t)M_ * D_ * 2);
  ushort* logits_bf = (ushort*)alloc((size_t)M_ * V_ * 2);
  float* f_lg = (float*)alloc((size_t)B_ * S_ * E_ * 4);
  float* f_pv = (float*)alloc(M_ * 4);
  float* f_mode = (float*)alloc(M_ * 4);
  float* f_loss = (float*)alloc(64);

  // global weight casts
  castTo(stream, word_emb, w_emb, (size_t)V_ * D_);
  castTo(stream, out_w, w_out, (size_t)D_ * D_);
  castTo(stream, copy_w, w_cp, (size_t)D_ * D_);
  castTo(stream, encoder_rep, enc_bf, (size_t)ME_ * D_);
  enct_kernel<<<(ME_ * D_) / 256, 256, 0, stream>>>(encoder_rep, encT_bf);
  pos_emb_kernel<<<(S_ * D_ + 255) / 256, 256, 0, stream>>>(r_bf);
  embed_kernel<<<(M_ * D_) / 256, 256, 0, stream>>>(decode_input, word_emb, f_core, core_bf);

  for (int l = 0; l < L_; ++l) {
    // cast this layer's weights
    castTo(stream, qkv_w + (size_t)l * 3 * D_ * D_, wl_qkv, (size_t)3 * D_ * D_);
    castTo(stream, r_w + (size_t)l * D_ * D_, wl_r, (size_t)D_ * D_);
    castTo(stream, o_w + (size_t)l * D_ * D_, wl_o, (size_t)D_ * D_);
    castTo(stream, kv_w + (size_t)l * 2 * D_ * D_, wl_kv, (size_t)2 * D_ * D_);
    castTo(stream, q_w + (size_t)l * D_ * D_, wl_q, (size_t)D_ * D_);
    castTo(stream, io_w + (size_t)l * D_ * D_, wl_io, (size_t)D_ * D_);
    castTo(stream, ffn_w1 + (size_t)l * FF_ * D_, wl_f1, (size_t)FF_ * D_);
    castTo(stream, ffn_w2 + (size_t)l * FF_ * D_, wl_f2, (size_t)FF_ * D_);

    // self-attention
    gw(stream, 1, core_bf, wl_qkv, nullptr, heads_bf, M_, 3 * D_, D_, D_, 0, D_, 0, 3 * D_, 0, 1, 0);
    gw(stream, 1, r_bf, wl_r, nullptr, rkproj_bf, S_, D_, D_, D_, 0, D_, 0, D_, 0, 1, 0);
    rkprep_kernel<<<(H_ * S_ * DH_) / 256, 256, 0, stream>>>(rkproj_bf, rk_bf);
    prep1_kernel<<<(M_ * D_) / 256, 256, 0, stream>>>(heads_bf, rw_bias + (size_t)l * D_,
                                                      rr_bias + (size_t)l * D_, qrw_bf, qrr_bf, k_bf);
    vtrans_kernel<<<dim3(B_ * H_, 1), 256, 0, stream>>>(heads_bf, vT_bf, 3 * D_, 2 * D_, S_);
    gw(stream, 0, qrw_bf, k_bf, nullptr, f_AC, S_, S_, DH_, 64, 8192, 64, 8192, 128, 16384, B_ * H_, 0);
    gw(stream, 0, qrr_bf, rk_bf, nullptr, f_BD, S_, S_, DH_, 64, 8192, 64, 8192, 128, 16384, B_ * H_, H_);
    softmax1_kernel<<<B_ * H_ * S_, 128, 0, stream>>>(f_AC, f_BD, prob_bf);
    gn(stream, prob_bf, vT_bf, f_vec, S_, S_, 128, 16384, 128, 8192, 64, 8192, B_ * H_);
    repack_kernel<<<(M_ * D_) / 256, 256, 0, stream>>>(f_vec, attnA_bf);
    gw(stream, 0, attnA_bf, wl_o, nullptr, f_tmp, M_, D_, D_, D_, 0, D_, 0, D_, 0, 1, 0);
    addln_kernel<<<M_, 256, 0, stream>>>(f_core, f_tmp, ln1_g + (size_t)l * D_, ln1_b + (size_t)l * D_, f_x, x_bf);

    // cross-attention
    gw(stream, 1, encT_bf, wl_kv, nullptr, kvproj_bf, ME_, 2 * D_, D_, D_, 0, D_, 0, 2 * D_, 0, 1, 0);
    gw(stream, 1, x_bf, wl_q, nullptr, qproj_bf, M_, D_, D_, D_, 0, D_, 0, D_, 0, 1, 0);
    scat_kernel<<<(M_ * D_) / 256, 256, 0, stream>>>(qproj_bf, q2_bf, 7, D_, 0, M_ * D_);
    scat_kernel<<<(B_ * H_ * E_ * DH_) / 256, 256, 0, stream>>>(kvproj_bf, k2_bf, 9, 2 * D_, 0,
                                                                B_ * H_ * E_ * DH_);
    vtrans_kernel<<<dim3(B_ * H_, E_ / 128), 256, 0, stream>>>(kvproj_bf, v2T_bf, 2 * D_, D_, E_);
    gw(stream, 0, q2_bf, k2_bf, nullptr, f_sc2, S_, E_, DH_, 64, 8192, 64, 32768, 512, 65536, B_ * H_, 0);
    softmax2_kernel<<<B_ * H_ * S_, 256, 0, stream>>>(f_sc2, input_mask, prob2_bf);
    gn(stream, prob2_bf, v2T_bf, f_vec, S_, E_, 512, 65536, 512, 32768, 64, 8192, B_ * H_);
    repack_kernel<<<(M_ * D_) / 256, 256, 0, stream>>>(f_vec, attnA_bf);
    gw(stream, 0, attnA_bf, wl_io, nullptr, f_tmp, M_, D_, D_, D_, 0, D_, 0, D_, 0, 1, 0);
    addln_kernel<<<M_, 256, 0, stream>>>(f_x, f_tmp, ln2_g + (size_t)l * D_, ln2_b + (size_t)l * D_, f_y, y_bf);

    // FFN
    gw(stream, 4, y_bf, wl_f1, ffn_b1 + (size_t)l * FF_, ffnh_bf, M_, FF_, D_, D_, 0, D_, 0, FF_, 0, 1, 0);
    gw(stream, 2, ffnh_bf, wl_f2, ffn_b2 + (size_t)l * D_, f_tmp, M_, D_, FF_, FF_, 0, FF_, 0, D_, 0, 1, 0);
    addln_kernel<<<M_, 256, 0, stream>>>(f_y, f_tmp, ln3_g + (size_t)l * D_, ln3_b + (size_t)l * D_, f_core, core_bf);
  }

  // heads
  gw(stream, 3, core_bf, w_out, out_b, fout_bf, M_, D_, D_, D_, 0, D_, 0, D_, 0, 1, 0);
  gw(stream, 3, core_bf, w_cp, copy_b, copyh_bf, M_, D_, D_, D_, 0, D_, 0, D_, 0, 1, 0);
  mode_kernel<<<M_, 256, 0, stream>>>(f_core, mode_w, mode_b, f_mode);
  gw(stream, 1, fout_bf, w_emb, nullptr, logits_bf, M_, V_, D_, D_, 0, D_, 0, V_, 0, 1, 0);
  vocabstats_kernel<<<M_, 256, 0, stream>>>(logits_bf, decode_target, f_pv);
  gw(stream, 0, copyh_bf, enc_bf, nullptr, f_lg, S_, E_, D_, (long long)B_ * D_, D_, D_,
     (long long)E_ * D_, E_, (long long)S_ * E_, B_, 0);

  hipMemsetAsync(f_loss, 0, 2 * sizeof(float), stream);
  final_kernel<<<dim3(S_, B_), 256, 0, stream>>>(f_lg, input_ids, input_mask, decode_target,
                                                 f_mode, f_pv, f_loss);
  writeout_kernel<<<1, 64, 0, stream>>>(f_loss, out);
}

// Round 3
// 1944.870 us; speedup vs baseline: 4.9552x; 1.2254x over previous
//
#include <hip/hip_runtime.h>
#include <math.h>

#define B_ 8
#define S_ 128
#define E_ 512
#define D_ 1024
#define H_ 16
#define L_ 4
#define V_ 32000
#define DH_ 64
#define FF_ 4096
#define M_ 1024      // S_*B_ rows, row = s*B_+b
#define ME_ 4096     // E_*B_ rows, row = e*B_+b
#define NT_ 250      // V_/128 vocab tiles
#define SCALE_F 0.125f
#define NEGV (-1e30f)

typedef __attribute__((ext_vector_type(8))) short short8;
typedef __attribute__((ext_vector_type(4))) float f32x4;

// ---------------- helpers ----------------
__device__ __forceinline__ float bf2f(ushort u) {
  union { unsigned int u32; float f; } v; v.u32 = ((unsigned int)u) << 16; return v.f;
}
__device__ __forceinline__ ushort f2bf(float x) {
  union { float f; unsigned int u; } v; v.f = x;
  unsigned int r = v.u + 0x7fff + ((v.u >> 16) & 1);
  return (ushort)(r >> 16);
}
__device__ __forceinline__ void gl_lds16(const ushort* g, ushort* l) {
  __builtin_amdgcn_global_load_lds((const __attribute__((address_space(1))) void*)g,
                                   (__attribute__((address_space(3))) void*)l, 16, 0, 0);
}

__device__ __forceinline__ float warp_reduce_sum(float v) {
#pragma unroll
  for (int o = 32; o > 0; o >>= 1) v += __shfl_down(v, o);
  return v;
}
__device__ __forceinline__ float warp_reduce_max(float v) {
#pragma unroll
  for (int o = 32; o > 0; o >>= 1) v = fmaxf(v, __shfl_down(v, o));
  return v;
}
__device__ __forceinline__ float block_reduce_sum(float v, float* sred) {
  v = warp_reduce_sum(v);
  __syncthreads();
  if ((threadIdx.x & 63) == 0) sred[threadIdx.x >> 6] = v;
  __syncthreads();
  float s = 0.0f;
  int nw = blockDim.x >> 6;
  for (int w = 0; w < nw; ++w) s += sred[w];
  return s;
}
__device__ __forceinline__ float block_reduce_max(float v, float* sred) {
  v = warp_reduce_max(v);
  __syncthreads();
  if ((threadIdx.x & 63) == 0) sred[threadIdx.x >> 6] = v;
  __syncthreads();
  float s = -3.4e38f;
  int nw = blockDim.x >> 6;
  for (int w = 0; w < nw; ++w) s = fmaxf(s, sred[w]);
  return s;
}

// ---------------- cast / setup ----------------
__global__ __launch_bounds__(256) void castf_kernel(const float* __restrict__ in,
                                                    ushort* __restrict__ out, int n4) {
  int t = blockIdx.x * 256 + threadIdx.x;
  if (t >= n4) return;
  float4 v = ((const float4*)in)[t];
  ushort4 o;
  o.x = f2bf(v.x); o.y = f2bf(v.y); o.z = f2bf(v.z); o.w = f2bf(v.w);
  ((ushort4*)out)[t] = o;
}

// encoder_rep [b,e,d] -> rows (e*B+b)
__global__ __launch_bounds__(256) void enct_kernel(const float* __restrict__ enc,
                                                   ushort* __restrict__ encT) {
  int t = blockIdx.x * 256 + threadIdx.x;
  if (t >= ME_ * D_) return;
  int d = t & (D_ - 1);
  int row = t >> 10;
  int e = row >> 3, b = row & 7;
  encT[t] = f2bf(enc[((size_t)b * E_ + e) * D_ + d]);
}

__global__ __launch_bounds__(256) void pos_emb_kernel(ushort* __restrict__ r) {
  int t = blockIdx.x * 256 + threadIdx.x;
  if (t >= S_ * D_) return;
  int i = t / D_, j = t % D_;
  float pos = (float)(S_ - 1 - i);
  int jj = (j < D_ / 2) ? j : (j - D_ / 2);
  float invf = powf(10000.0f, -(float)(2 * jj) / (float)D_);
  float a = pos * invf;
  r[t] = f2bf((j < D_ / 2) ? sinf(a) : cosf(a));
}

__global__ __launch_bounds__(256) void embed_kernel(const int* __restrict__ ids,
                                                    const float* __restrict__ emb,
                                                    float* __restrict__ core,
                                                    ushort* __restrict__ core_bf) {
  int t = blockIdx.x * 256 + threadIdx.x;
  if (t >= M_ * D_) return;
  int d = t & (D_ - 1);
  int row = t >> 10;
  int s = row >> 3, b = row & 7;
  float v = emb[(size_t)ids[b * S_ + s] * D_ + d];
  core[t] = v;
  core_bf[t] = f2bf(v);
}

// ---------------- bf16 MFMA GEMM, 128x128 tile, batched + split-K ----------------
// EPI: 0 f32, 1 bf16, 3 bf16+bias, 4 bf16+bias+gelu
template <int EPI>
__global__ __launch_bounds__(256) void gemm_w_kernel(
    const ushort* __restrict__ A, const ushort* __restrict__ Bm,
    const float* __restrict__ bias, void* __restrict__ Cv,
    int M, int N, int K, int ksplit,
    long long Arow, long long Abatch, long long Brow, long long Bbatch,
    long long Crow, long long Cbatch, long long Csplit) {
  __shared__ ushort lA[128 * 32];
  __shared__ ushort lB[128 * 32];
  int tid = threadIdx.x;
  int bz = blockIdx.z;
  int batch = bz / ksplit, split = bz % ksplit;
  int kLen = K / ksplit, kStart = split * kLen;
  const ushort* Ab = A + (size_t)batch * Abatch;
  const ushort* Bb = Bm + (size_t)batch * Bbatch;
  int bm = blockIdx.y * 128, bn = blockIdx.x * 128;
  int lane = tid & 63, wave = tid >> 6;
  int wrow = (wave >> 1) * 64, wcol = (wave & 1) * 64;
  int quad = lane >> 4, l16 = lane & 15;
  f32x4 acc[4][4];
#pragma unroll
  for (int i = 0; i < 4; ++i)
#pragma unroll
    for (int j = 0; j < 4; ++j) { acc[i][j][0] = 0.f; acc[i][j][1] = 0.f; acc[i][j][2] = 0.f; acc[i][j][3] = 0.f; }
  int r0 = tid >> 2, c0 = (tid & 3) * 8;
  int r1 = (tid + 256) >> 2;
  for (int k0 = kStart; k0 < kStart + kLen; k0 += 32) {
    __syncthreads();
    gl_lds16(Ab + (size_t)(bm + r0) * Arow + k0 + c0, &lA[(size_t)tid * 8]);
    gl_lds16(Ab + (size_t)(bm + r1) * Arow + k0 + c0, &lA[(size_t)(256 + tid) * 8]);
    gl_lds16(Bb + (size_t)(bn + r0) * Brow + k0 + c0, &lB[(size_t)tid * 8]);
    gl_lds16(Bb + (size_t)(bn + r1) * Brow + k0 + c0, &lB[(size_t)(256 + tid) * 8]);
    __syncthreads();
    short8 af[4], bfr[4];
#pragma unroll
    for (int mi = 0; mi < 4; ++mi)
      af[mi] = *(const short8*)&lA[(size_t)(wrow + mi * 16 + l16) * 32 + quad * 8];
#pragma unroll
    for (int ni = 0; ni < 4; ++ni)
      bfr[ni] = *(const short8*)&lB[(size_t)(wcol + ni * 16 + l16) * 32 + quad * 8];
#pragma unroll
    for (int mi = 0; mi < 4; ++mi)
#pragma unroll
      for (int ni = 0; ni < 4; ++ni)
        acc[mi][ni] = __builtin_amdgcn_mfma_f32_16x16x32_bf16(af[mi], bfr[ni], acc[mi][ni], 0, 0, 0);
  }
#pragma unroll
  for (int mi = 0; mi < 4; ++mi) {
    int row0 = bm + wrow + mi * 16 + quad * 4;
#pragma unroll
    for (int ni = 0; ni < 4; ++ni) {
      int col = bn + wcol + ni * 16 + l16;
      float bv = 0.f;
      if (EPI >= 3) bv = bias[col];
#pragma unroll
      for (int r = 0; r < 4; ++r) {
        float v = acc[mi][ni][r] + bv;
        if (EPI == 4) v = 0.5f * v * (1.0f + erff(v * 0.70710678118654752f));
        size_t ci = (size_t)split * Csplit + (size_t)batch * Cbatch + (size_t)(row0 + r) * Crow + col;
        if (EPI == 0) ((float*)Cv)[ci] = v;
        else ((ushort*)Cv)[ci] = f2bf(v);
      }
    }
  }
}

// ---------------- vocab GEMM with fused softmax-stats epilogue ----------------
// A = headout_bf (row stride 2048), B = w_emb. grid (M/128, V/128), x = row tiles (fast)
__global__ __launch_bounds__(256) void vocab_kernel(const ushort* __restrict__ A,
                                                    const ushort* __restrict__ Bm,
                                                    float* __restrict__ tmax,
                                                    float* __restrict__ tsum) {
  __shared__ ushort lA[128 * 32];
  __shared__ ushort lB[128 * 32];
  __shared__ float smax[2][128];
  __shared__ float ssum[2][128];
  int tid = threadIdx.x;
  int bm = blockIdx.x * 128;           // rows (fast dim -> co-resident share B)
  int bn = blockIdx.y * 128;           // vocab
  int lane = tid & 63, wave = tid >> 6;
  int wrow = (wave >> 1) * 64, half = wave & 1, wcol = half * 64;
  int quad = lane >> 4, l16 = lane & 15;
  f32x4 acc[4][4];
#pragma unroll
  for (int i = 0; i < 4; ++i)
#pragma unroll
    for (int j = 0; j < 4; ++j) { acc[i][j][0] = 0.f; acc[i][j][1] = 0.f; acc[i][j][2] = 0.f; acc[i][j][3] = 0.f; }
  int r0 = tid >> 2, c0 = (tid & 3) * 8;
  int r1 = (tid + 256) >> 2;
  for (int k0 = 0; k0 < D_; k0 += 32) {
    __syncthreads();
    gl_lds16(A + (size_t)(bm + r0) * 2048 + k0 + c0, &lA[(size_t)tid * 8]);
    gl_lds16(A + (size_t)(bm + r1) * 2048 + k0 + c0, &lA[(size_t)(256 + tid) * 8]);
    gl_lds16(Bm + (size_t)(bn + r0) * D_ + k0 + c0, &lB[(size_t)tid * 8]);
    gl_lds16(Bm + (size_t)(bn + r1) * D_ + k0 + c0, &lB[(size_t)(256 + tid) * 8]);
    __syncthreads();
    short8 af[4], bfr[4];
#pragma unroll
    for (int mi = 0; mi < 4; ++mi)
      af[mi] = *(const short8*)&lA[(size_t)(wrow + mi * 16 + l16) * 32 + quad * 8];
#pragma unroll
    for (int ni = 0; ni < 4; ++ni)
      bfr[ni] = *(const short8*)&lB[(size_t)(wcol + ni * 16 + l16) * 32 + quad * 8];
#pragma unroll
    for (int mi = 0; mi < 4; ++mi)
#pragma unroll
      for (int ni = 0; ni < 4; ++ni)
        acc[mi][ni] = __builtin_amdgcn_mfma_f32_16x16x32_bf16(af[mi], bfr[ni], acc[mi][ni], 0, 0, 0);
  }
  // per-row max over this wave's 64 cols
#pragma unroll
  for (int mi = 0; mi < 4; ++mi)
#pragma unroll
    for (int r = 0; r < 4; ++r) {
      float lm = -3.4e38f;
#pragma unroll
      for (int ni = 0; ni < 4; ++ni) lm = fmaxf(lm, acc[mi][ni][r]);
#pragma unroll
      for (int o = 1; o < 16; o <<= 1) lm = fmaxf(lm, __shfl_xor(lm, o));
      if (l16 == 0) smax[half][wrow + mi * 16 + quad * 4 + r] = lm;
    }
  __syncthreads();
#pragma unroll
  for (int mi = 0; mi < 4; ++mi)
#pragma unroll
    for (int r = 0; r < 4; ++r) {
      int row = wrow + mi * 16 + quad * 4 + r;
      float m = fmaxf(smax[0][row], smax[1][row]);
      float ls = 0.f;
#pragma unroll
      for (int ni = 0; ni < 4; ++ni) ls += __expf(acc[mi][ni][r] - m);
#pragma unroll
      for (int o = 1; o < 16; o <<= 1) ls += __shfl_xor(ls, o);
      if (l16 == 0) ssum[half][row] = ls;
    }
  __syncthreads();
  if (tid < 128) {
    float m = fmaxf(smax[0][tid], smax[1][tid]);
    float s = ssum[0][tid] + ssum[1][tid];
    tmax[(size_t)(bm + tid) * NT_ + blockIdx.y] = m;
    tsum[(size_t)(bm + tid) * NT_ + blockIdx.y] = s;
  }
}

__global__ __launch_bounds__(256) void vocab_combine_kernel(const float* __restrict__ tmax,
                                                            const float* __restrict__ tsum,
                                                            float* __restrict__ rmax,
                                                            float* __restrict__ rsum) {
  __shared__ float sred[4];
  int m = blockIdx.x;
  float mx = -3.4e38f;
  for (int t = threadIdx.x; t < NT_; t += 256) mx = fmaxf(mx, tmax[(size_t)m * NT_ + t]);
  mx = block_reduce_max(mx, sred);
  float s = 0.f;
  for (int t = threadIdx.x; t < NT_; t += 256)
    s += tsum[(size_t)m * NT_ + t] * expf(tmax[(size_t)m * NT_ + t] - mx);
  s = block_reduce_sum(s, sred);
  if (threadIdx.x == 0) { rmax[m] = mx; rsum[m] = s; }
}

__global__ __launch_bounds__(256) void tlogit_kernel(const ushort* __restrict__ headout,
                                                     const ushort* __restrict__ emb,
                                                     const int* __restrict__ tgt,
                                                     float* __restrict__ tl) {
  __shared__ float sred[4];
  int m = blockIdx.x;
  int s = m >> 3, b = m & 7;
  int t = tgt[b * S_ + s];
  const ushort* a = headout + (size_t)m * 2048;
  const ushort* w = emb + (size_t)t * D_;
  float acc = 0.f;
  for (int i = threadIdx.x; i < D_; i += 256) acc += bf2f(a[i]) * bf2f(w[i]);
  acc = block_reduce_sum(acc, sred);
  if (threadIdx.x == 0) tl[m] = acc;
}

// ---------------- fused self-attention, one block per (b,h) ----------------
__global__ __launch_bounds__(256) void attn1_fused_kernel(const ushort* __restrict__ heads,
                                                          const ushort* __restrict__ rkproj,
                                                          const float* __restrict__ rw,
                                                          const float* __restrict__ rr,
                                                          ushort* __restrict__ attnA) {
  __shared__ float score[128][129];   // 66 KB
  __shared__ ushort pP[128][136];     // 34.8 KB
  __shared__ ushort vT[64][136];      // 17.4 KB
  int bz = blockIdx.x;
  int b = bz >> 4, n = bz & 15;
  int tid = threadIdx.x, lane = tid & 63, wave = tid >> 6;
  int quad = lane >> 4, l16 = lane & 15;
  int wrow = wave * 32;

  // stage V transposed: vT[d][j]
  {
    int j = tid >> 1, dbase = (tid & 1) * 32;
    const ushort* src = heads + (size_t)(j * 8 + b) * 3072 + 2048 + n * 64 + dbase;
#pragma unroll
    for (int c8 = 0; c8 < 4; ++c8) {
      short8 v8 = *(const short8*)(src + c8 * 8);
#pragma unroll
      for (int cc = 0; cc < 8; ++cc) vT[dbase + c8 * 8 + cc][j] = (ushort)v8[cc];
    }
  }

  // Q fragments with biases
  short8 qrw[2][2], qrr[2][2];
#pragma unroll
  for (int mi = 0; mi < 2; ++mi) {
    int i = wrow + mi * 16 + l16;
    const ushort* qp = heads + (size_t)(i * 8 + b) * 3072 + n * 64;
#pragma unroll
    for (int kc = 0; kc < 2; ++kc) {
      int k0 = kc * 32 + quad * 8;
      short8 qv = *(const short8*)(qp + k0);
      short8 w, rv;
#pragma unroll
      for (int t = 0; t < 8; ++t) {
        float q = bf2f((ushort)qv[t]);
        w[t] = (short)f2bf(q + rw[n * 64 + k0 + t]);
        rv[t] = (short)f2bf(q + rr[n * 64 + k0 + t]);
      }
      qrw[mi][kc] = w; qrr[mi][kc] = rv;
    }
  }

  // pass 1: AC -> score LDS
  {
    f32x4 acc[2][8];
#pragma unroll
    for (int i = 0; i < 2; ++i)
#pragma unroll
      for (int j = 0; j < 8; ++j) { acc[i][j][0]=0.f; acc[i][j][1]=0.f; acc[i][j][2]=0.f; acc[i][j][3]=0.f; }
#pragma unroll
    for (int kc = 0; kc < 2; ++kc) {
      int k0 = kc * 32 + quad * 8;
      short8 kf[8];
#pragma unroll
      for (int ni = 0; ni < 8; ++ni) {
        int j = ni * 16 + l16;
        kf[ni] = *(const short8*)(heads + (size_t)(j * 8 + b) * 3072 + 1024 + n * 64 + k0);
      }
#pragma unroll
      for (int mi = 0; mi < 2; ++mi)
#pragma unroll
        for (int ni = 0; ni < 8; ++ni)
          acc[mi][ni] = __builtin_amdgcn_mfma_f32_16x16x32_bf16(qrw[mi][kc], kf[ni], acc[mi][ni], 0, 0, 0);
    }
#pragma unroll
    for (int mi = 0; mi < 2; ++mi)
#pragma unroll
      for (int ni = 0; ni < 8; ++ni)
#pragma unroll
        for (int r = 0; r < 4; ++r)
          score[wrow + mi * 16 + quad * 4 + r][ni * 16 + l16] = acc[mi][ni][r];
  }
  // pass 2: BD pre-shift, add into score with rel-shift mapping
  {
    f32x4 acc[2][8];
#pragma unroll
    for (int i = 0; i < 2; ++i)
#pragma unroll
      for (int j = 0; j < 8; ++j) { acc[i][j][0]=0.f; acc[i][j][1]=0.f; acc[i][j][2]=0.f; acc[i][j][3]=0.f; }
#pragma unroll
    for (int kc = 0; kc < 2; ++kc) {
      int k0 = kc * 32 + quad * 8;
      short8 rkf[8];
#pragma unroll
      for (int ni = 0; ni < 8; ++ni) {
        int jp = ni * 16 + l16;
        rkf[ni] = *(const short8*)(rkproj + (size_t)jp * 1024 + n * 64 + k0);
      }
#pragma unroll
      for (int mi = 0; mi < 2; ++mi)
#pragma unroll
        for (int ni = 0; ni < 8; ++ni)
          acc[mi][ni] = __builtin_amdgcn_mfma_f32_16x16x32_bf16(qrr[mi][kc], rkf[ni], acc[mi][ni], 0, 0, 0);
    }
#pragma unroll
    for (int mi = 0; mi < 2; ++mi)
#pragma unroll
      for (int r = 0; r < 4; ++r) {
        int i = wrow + mi * 16 + quad * 4 + r;
#pragma unroll
        for (int ni = 0; ni < 8; ++ni) {
          int jp = ni * 16 + l16;
          if (jp >= 127 - i) score[i][jp - 127 + i] += acc[mi][ni][r];
        }
      }
  }
  // softmax (rows owned by same wave): row = tid>>1, half cols each
  {
    int row = tid >> 1, halfc = (tid & 1) * 64;
    float mx = -3.4e38f;
    for (int c = halfc; c < halfc + 64; ++c) {
      float v = (c <= row) ? score[row][c] * SCALE_F : -3.4e38f;
      mx = fmaxf(mx, v);
    }
    mx = fmaxf(mx, __shfl_xor(mx, 1));
    float s = 0.f;
    for (int c = halfc; c < halfc + 64; ++c) {
      float e = (c <= row) ? __expf(score[row][c] * SCALE_F - mx) : 0.f;
      score[row][c] = e;
      s += e;
    }
    s += __shfl_xor(s, 1);
    float inv = 1.0f / s;
    for (int c = halfc; c < halfc + 64; ++c) pP[row][c] = f2bf(score[row][c] * inv);
  }
  __syncthreads();  // vT + pP ready for all
  // PV: O[i][d] = sum_j P[i][j] V[j][d]
  {
    f32x4 acc[2][4];
#pragma unroll
    for (int i = 0; i < 2; ++i)
#pragma unroll
      for (int j = 0; j < 4; ++j) { acc[i][j][0]=0.f; acc[i][j][1]=0.f; acc[i][j][2]=0.f; acc[i][j][3]=0.f; }
#pragma unroll
    for (int kc = 0; kc < 4; ++kc) {
      int k0 = kc * 32 + quad * 8;
      short8 pf[2], vf[4];
#pragma unroll
      for (int mi = 0; mi < 2; ++mi)
        pf[mi] = *(const short8*)&pP[wrow + mi * 16 + l16][k0];
#pragma unroll
      for (int ni = 0; ni < 4; ++ni)
        vf[ni] = *(const short8*)&vT[ni * 16 + l16][k0];
#pragma unroll
      for (int mi = 0; mi < 2; ++mi)
#pragma unroll
        for (int ni = 0; ni < 4; ++ni)
          acc[mi][ni] = __builtin_amdgcn_mfma_f32_16x16x32_bf16(pf[mi], vf[ni], acc[mi][ni], 0, 0, 0);
    }
#pragma unroll
    for (int mi = 0; mi < 2; ++mi)
#pragma unroll
      for (int r = 0; r < 4; ++r) {
        int i = wrow + mi * 16 + quad * 4 + r;
#pragma unroll
        for (int ni = 0; ni < 4; ++ni)
          attnA[(size_t)(i * 8 + b) * 1024 + n * 64 + ni * 16 + l16] = f2bf(acc[mi][ni][r]);
      }
  }
}

// ---------------- fused cross-attention (flash over 4 E-tiles), block per (b,h) --------
__global__ __launch_bounds__(256) void attn2_fused_kernel(const float* __restrict__ q0,
                                                          const float* __restrict__ q1,
                                                          const ushort* __restrict__ kvproj,
                                                          const float* __restrict__ mask,
                                                          ushort* __restrict__ attnA) {
  __shared__ ushort vT[64][136];
  __shared__ ushort pP[128][136];
  __shared__ float mtile[128];
  int bz = blockIdx.x;
  int b = bz >> 4, n = bz & 15;
  int tid = threadIdx.x, lane = tid & 63, wave = tid >> 6;
  int quad = lane >> 4, l16 = lane & 15;
  int wrow = wave * 32;
  // Q frags: q0+q1 (split-K halves), f32 -> bf16
  short8 qf[2][2];
#pragma unroll
  for (int mi = 0; mi < 2; ++mi) {
    int i = wrow + mi * 16 + l16;
    size_t base = (size_t)(i * 8 + b) * 1024 + n * 64;
#pragma unroll
    for (int kc = 0; kc < 2; ++kc) {
      int k0 = kc * 32 + quad * 8;
      short8 v;
#pragma unroll
      for (int t = 0; t < 8; ++t) v[t] = (short)f2bf(q0[base + k0 + t] + q1[base + k0 + t]);
      qf[mi][kc] = v;
    }
  }
  float m_run[2][4], l_run[2][4];
#pragma unroll
  for (int mi = 0; mi < 2; ++mi)
#pragma unroll
    for (int r = 0; r < 4; ++r) { m_run[mi][r] = -3.0e38f; l_run[mi][r] = 0.f; }
  f32x4 accO[2][4];
#pragma unroll
  for (int i = 0; i < 2; ++i)
#pragma unroll
    for (int j = 0; j < 4; ++j) { accO[i][j][0]=0.f; accO[i][j][1]=0.f; accO[i][j][2]=0.f; accO[i][j][3]=0.f; }

  for (int et = 0; et < 4; ++et) {
    __syncthreads();  // previous tile's PV done before restaging
    // stage V2 tile transposed + mask tile
    {
      int j = tid >> 1, dbase = (tid & 1) * 32;
      int e = et * 128 + j;
      const ushort* src = kvproj + (size_t)(e * 8 + b) * 2048 + 1024 + n * 64 + dbase;
#pragma unroll
      for (int c8 = 0; c8 < 4; ++c8) {
        short8 v8 = *(const short8*)(src + c8 * 8);
#pragma unroll
        for (int cc = 0; cc < 8; ++cc) vT[dbase + c8 * 8 + cc][j] = (ushort)v8[cc];
      }
      if (tid < 128) mtile[tid] = (1.0f - mask[b * E_ + et * 128 + tid]) * NEGV;
    }
    // S tile
    f32x4 accS[2][8];
#pragma unroll
    for (int i = 0; i < 2; ++i)
#pragma unroll
      for (int j = 0; j < 8; ++j) { accS[i][j][0]=0.f; accS[i][j][1]=0.f; accS[i][j][2]=0.f; accS[i][j][3]=0.f; }
#pragma unroll
    for (int kc = 0; kc < 2; ++kc) {
      int k0 = kc * 32 + quad * 8;
      short8 kf[8];
#pragma unroll
      for (int ni = 0; ni < 8; ++ni) {
        int e = et * 128 + ni * 16 + l16;
        kf[ni] = *(const short8*)(kvproj + (size_t)(e * 8 + b) * 2048 + n * 64 + k0);
      }
#pragma unroll
      for (int mi = 0; mi < 2; ++mi)
#pragma unroll
        for (int ni = 0; ni < 8; ++ni)
          accS[mi][ni] = __builtin_amdgcn_mfma_f32_16x16x32_bf16(qf[mi][kc], kf[ni], accS[mi][ni], 0, 0, 0);
    }
    __syncthreads();  // vT, mtile ready
    // online softmax per owned row
#pragma unroll
    for (int mi = 0; mi < 2; ++mi)
#pragma unroll
      for (int r = 0; r < 4; ++r) {
        float v[8];
        float vmax = -3.4e38f;
#pragma unroll
        for (int ni = 0; ni < 8; ++ni) {
          v[ni] = accS[mi][ni][r] * SCALE_F + mtile[ni * 16 + l16];
          vmax = fmaxf(vmax, v[ni]);
        }
#pragma unroll
        for (int o = 1; o < 16; o <<= 1) vmax = fmaxf(vmax, __shfl_xor(vmax, o));
        float mnew = fmaxf(m_run[mi][r], vmax);
        float alpha = __expf(m_run[mi][r] - mnew);
        float ls = 0.f;
        int row = wrow + mi * 16 + quad * 4 + r;
#pragma unroll
        for (int ni = 0; ni < 8; ++ni) {
          float p = __expf(v[ni] - mnew);
          ls += p;
          pP[row][ni * 16 + l16] = f2bf(p);
        }
#pragma unroll
        for (int o = 1; o < 16; o <<= 1) ls += __shfl_xor(ls, o);
        l_run[mi][r] = l_run[mi][r] * alpha + ls;
        m_run[mi][r] = mnew;
#pragma unroll
        for (int ni = 0; ni < 4; ++ni) accO[mi][ni][r] *= alpha;
      }
    // PV accumulate (pP rows own-wave, vT via sync above)
#pragma unroll
    for (int kc = 0; kc < 4; ++kc) {
      int k0 = kc * 32 + quad * 8;
      short8 pf[2], vf[4];
#pragma unroll
      for (int mi = 0; mi < 2; ++mi)
        pf[mi] = *(const short8*)&pP[wrow + mi * 16 + l16][k0];
#pragma unroll
      for (int ni = 0; ni < 4; ++ni)
        vf[ni] = *(const short8*)&vT[ni * 16 + l16][k0];
#pragma unroll
      for (int mi = 0; mi < 2; ++mi)
#pragma unroll
        for (int ni = 0; ni < 4; ++ni)
          accO[mi][ni] = __builtin_amdgcn_mfma_f32_16x16x32_bf16(pf[mi], vf[ni], accO[mi][ni], 0, 0, 0);
    }
  }
  // finalize
#pragma unroll
  for (int mi = 0; mi < 2; ++mi)
#pragma unroll
    for (int r = 0; r < 4; ++r) {
      int i = wrow + mi * 16 + quad * 4 + r;
      float inv = 1.0f / l_run[mi][r];
#pragma unroll
      for (int ni = 0; ni < 4; ++ni)
        attnA[(size_t)(i * 8 + b) * 1024 + n * 64 + ni * 16 + l16] = f2bf(accO[mi][ni][r] * inv);
    }
}

// ---------------- add + layernorm with split-sum + optional bias ----------------
__global__ __launch_bounds__(256) void addln_kernel(const float* __restrict__ a,
                                                    const float* __restrict__ c,
                                                    int nsplit, long long cstride,
                                                    const float* __restrict__ bias,
                                                    const float* __restrict__ g,
                                                    const float* __restrict__ bb,
                                                    float* __restrict__ out,
                                                    ushort* __restrict__ out_bf) {
  __shared__ float sred[4];
  int row = blockIdx.x;
  const float* pa = a + (size_t)row * D_;
  float vals[4];
  float s = 0.f;
#pragma unroll
  for (int it = 0; it < 4; ++it) {
    int idx = threadIdx.x + it * 256;
    float v = pa[idx];
    for (int sp = 0; sp < nsplit; ++sp) v += c[(size_t)sp * cstride + (size_t)row * D_ + idx];
    if (bias) v += bias[idx];
    vals[it] = v;
    s += v;
  }
  s = block_reduce_sum(s, sred);
  float mean = s * (1.0f / D_);
  float ss = 0.f;
#pragma unroll
  for (int it = 0; it < 4; ++it) {
    float dd = vals[it] - mean;
    ss += dd * dd;
  }
  ss = block_reduce_sum(ss, sred);
  float inv = rsqrtf(ss * (1.0f / D_) + 1e-5f);
#pragma unroll
  for (int it = 0; it < 4; ++it) {
    int idx = threadIdx.x + it * 256;
    float r = (vals[it] - mean) * inv * g[idx] + bb[idx];
    out[(size_t)row * D_ + idx] = r;
    out_bf[(size_t)row * D_ + idx] = f2bf(r);
  }
}

__global__ __launch_bounds__(256) void mode_kernel(const float* __restrict__ core,
                                                   const float* __restrict__ mode_w,
                                                   const float* __restrict__ mode_b,
                                                   float* __restrict__ mode_sig) {
  __shared__ float sred[4];
  int m = blockIdx.x;
  const float* a = core + (size_t)m * D_;
  float s = 0.f;
  for (int t = threadIdx.x; t < D_; t += 256) s += a[t] * mode_w[t];
  s = block_reduce_sum(s, sred);
  if (threadIdx.x == 0) mode_sig[m] = 1.0f / (1.0f + expf(-(s + mode_b[0])));
}

// ---------------- final: copy attention + loss ----------------
__global__ __launch_bounds__(256) void final_kernel(const float* __restrict__ lg,
                                                    const int* __restrict__ ids,
                                                    const float* __restrict__ mask,
                                                    const int* __restrict__ tgt,
                                                    const float* __restrict__ mode_sig,
                                                    const float* __restrict__ tlogit,
                                                    const float* __restrict__ rmax,
                                                    const float* __restrict__ rsum,
                                                    float* __restrict__ loss_acc) {
  __shared__ float sred[4];
  int s = blockIdx.x, b = blockIdx.y;
  int m = s * B_ + b;
  size_t base = (size_t)(b * S_ + s) * E_;
  const long long LGS = (long long)B_ * S_ * E_;
  int tg = tgt[b * S_ + s];
  float lv[2];
  float mx = -3.4e38f;
#pragma unroll
  for (int it = 0; it < 2; ++it) {
    int e = threadIdx.x + it * 256;
    float raw = 0.f;
#pragma unroll
    for (int sp = 0; sp < 4; ++sp) raw += lg[sp * LGS + base + e];
    raw += (1.0f - mask[b * E_ + e]) * NEGV;
    lv[it] = raw;
    mx = fmaxf(mx, raw);
  }
  mx = block_reduce_max(mx, sred);
  float ssum = 0.f, csum = 0.f;
#pragma unroll
  for (int it = 0; it < 2; ++it) {
    int e = threadIdx.x + it * 256;
    float ev = expf(lv[it] - mx);
    ssum += ev;
    if (ids[b * E_ + e] == tg) csum += ev;
  }
  ssum = block_reduce_sum(ssum, sred);
  csum = block_reduce_sum(csum, sred);
  if (threadIdx.x == 0) {
    float copy_p = csum / ssum;
    float pv = expf(tlogit[m] - rmax[m]) / rsum[m];
    float msig = mode_sig[m];
    float predict = pv * msig + (1.0f - msig) * copy_p;
    float valid = (tg != 0) ? 1.0f : 0.0f;
    atomicAdd(&loss_acc[0], -logf(predict + 1e-6f) * valid);
    atomicAdd(&loss_acc[1], valid);
  }
}

__global__ void writeout_kernel(const float* __restrict__ loss_acc, float* __restrict__ out) {
  if (threadIdx.x < B_) out[threadIdx.x] = loss_acc[0] / loss_acc[1];
}

// ---------------- host ----------------
static void gw(hipStream_t st, int epi, const ushort* A, const ushort* B, const float* bias,
               void* C, int M, int N, int K,
               long long Ar, long long Ab, long long Br, long long Bb,
               long long Cr, long long Cb, int nb, int ksplit, long long Csplit) {
  dim3 g(N / 128, M / 128, nb * ksplit);
  switch (epi) {
    case 0: gemm_w_kernel<0><<<g, 256, 0, st>>>(A, B, bias, C, M, N, K, ksplit, Ar, Ab, Br, Bb, Cr, Cb, Csplit); break;
    case 1: gemm_w_kernel<1><<<g, 256, 0, st>>>(A, B, bias, C, M, N, K, ksplit, Ar, Ab, Br, Bb, Cr, Cb, Csplit); break;
    case 3: gemm_w_kernel<3><<<g, 256, 0, st>>>(A, B, bias, C, M, N, K, ksplit, Ar, Ab, Br, Bb, Cr, Cb, Csplit); break;
    case 4: gemm_w_kernel<4><<<g, 256, 0, st>>>(A, B, bias, C, M, N, K, ksplit, Ar, Ab, Br, Bb, Cr, Cb, Csplit); break;
  }
}
static void castTo(hipStream_t st, const float* src, ushort* dst, size_t count) {
  int n4 = (int)(count / 4);
  castf_kernel<<<(n4 + 255) / 256, 256, 0, st>>>(src, dst, n4);
}

extern "C" void kernel_launch(void* const* d_in, const int* in_sizes, int n_in,
                              void* d_out, int out_size, void* d_ws, size_t ws_size,
                              hipStream_t stream) {
  const int* input_ids = (const int*)d_in[0];
  const float* encoder_rep = (const float*)d_in[1];
  const float* input_mask = (const float*)d_in[2];
  const int* decode_input = (const int*)d_in[3];
  const int* decode_target = (const int*)d_in[4];
  const float* word_emb = (const float*)d_in[5];
  const float* qkv_w = (const float*)d_in[6];
  const float* r_w = (const float*)d_in[7];
  const float* o_w = (const float*)d_in[8];
  const float* kv_w = (const float*)d_in[9];
  const float* q_w = (const float*)d_in[10];
  const float* io_w = (const float*)d_in[11];
  const float* rr_bias = (const float*)d_in[12];
  const float* rw_bias = (const float*)d_in[13];
  const float* ln1_g = (const float*)d_in[14];
  const float* ln1_b = (const float*)d_in[15];
  const float* ln2_g = (const float*)d_in[16];
  const float* ln2_b = (const float*)d_in[17];
  const float* ffn_w1 = (const float*)d_in[18];
  const float* ffn_b1 = (const float*)d_in[19];
  const float* ffn_w2 = (const float*)d_in[20];
  const float* ffn_b2 = (const float*)d_in[21];
  const float* ln3_g = (const float*)d_in[22];
  const float* ln3_b = (const float*)d_in[23];
  const float* out_w = (const float*)d_in[24];
  const float* out_b = (const float*)d_in[25];
  const float* copy_w = (const float*)d_in[26];
  const float* copy_b = (const float*)d_in[27];
  const float* mode_w = (const float*)d_in[28];
  const float* mode_b = (const float*)d_in[29];
  float* out = (float*)d_out;

  char* base = (char*)d_ws;
  size_t off = 0;
  auto alloc = [&](size_t bytes) -> void* {
    void* p = base + off;
    off = (off + bytes + 255) & ~(size_t)255;
    return p;
  };

  ushort* wl_qkv = (ushort*)alloc((size_t)3 * D_ * D_ * 2);
  ushort* wl_r = (ushort*)alloc((size_t)D_ * D_ * 2);
  ushort* wl_o = (ushort*)alloc((size_t)D_ * D_ * 2);
  ushort* wl_kv = (ushort*)alloc((size_t)2 * D_ * D_ * 2);
  ushort* wl_q = (ushort*)alloc((size_t)D_ * D_ * 2);
  ushort* wl_io = (ushort*)alloc((size_t)D_ * D_ * 2);
  ushort* wl_f1 = (ushort*)alloc((size_t)FF_ * D_ * 2);
  ushort* wl_f2 = (ushort*)alloc((size_t)FF_ * D_ * 2);
  ushort* w_emb = (ushort*)alloc((size_t)V_ * D_ * 2);
  ushort* w_oc = (ushort*)alloc((size_t)2048 * D_ * 2);
  float* b_oc = (float*)alloc(2048 * 4);
  ushort* enc_bf = (ushort*)alloc((size_t)ME_ * D_ * 2);
  ushort* encT_bf = (ushort*)alloc((size_t)ME_ * D_ * 2);
  ushort* r_bf = (ushort*)alloc((size_t)S_ * D_ * 2);
  ushort* rkproj_bf = (ushort*)alloc((size_t)S_ * D_ * 2);
  float* f_core = (float*)alloc((size_t)M_ * D_ * 4);
  ushort* core_bf = (ushort*)alloc((size_t)M_ * D_ * 2);
  ushort* heads_bf = (ushort*)alloc((size_t)M_ * 3 * D_ * 2);
  ushort* attnA_bf = (ushort*)alloc((size_t)M_ * D_ * 2);
  float* f_tmp = (float*)alloc((size_t)4 * M_ * D_ * 4);   // up to 4 split buffers
  float* f_x = (float*)alloc((size_t)M_ * D_ * 4);
  ushort* x_bf = (ushort*)alloc((size_t)M_ * D_ * 2);
  float* f_y = (float*)alloc((size_t)M_ * D_ * 4);
  ushort* y_bf = (ushort*)alloc((size_t)M_ * D_ * 2);
  ushort* kvproj_bf = (ushort*)alloc((size_t)ME_ * 2 * D_ * 2);
  float* f_q = (float*)alloc((size_t)2 * M_ * D_ * 4);      // q split buffers
  ushort* ffnh_bf = (ushort*)alloc((size_t)M_ * FF_ * 2);
  ushort* headout_bf = (ushort*)alloc((size_t)M_ * 2048 * 2);
  float* f_lg = (float*)alloc((size_t)4 * B_ * S_ * E_ * 4);
  float* f_tmax = (float*)alloc((size_t)M_ * NT_ * 4);
  float* f_tsum = (float*)alloc((size_t)M_ * NT_ * 4);
  float* f_rmax = (float*)alloc(M_ * 4);
  float* f_rsum = (float*)alloc(M_ * 4);
  float* f_tlogit = (float*)alloc(M_ * 4);
  float* f_mode = (float*)alloc(M_ * 4);
  float* f_loss = (float*)alloc(64);

  // global casts + setup
  castTo(stream, word_emb, w_emb, (size_t)V_ * D_);
  castTo(stream, out_w, w_oc, (size_t)D_ * D_);
  castTo(stream, copy_w, w_oc + (size_t)D_ * D_, (size_t)D_ * D_);
  hipMemcpyAsync(b_oc, out_b, D_ * 4, hipMemcpyDeviceToDevice, stream);
  hipMemcpyAsync(b_oc + D_, copy_b, D_ * 4, hipMemcpyDeviceToDevice, stream);
  castTo(stream, encoder_rep, enc_bf, (size_t)ME_ * D_);
  enct_kernel<<<(ME_ * D_) / 256, 256, 0, stream>>>(encoder_rep, encT_bf);
  pos_emb_kernel<<<(S_ * D_ + 255) / 256, 256, 0, stream>>>(r_bf);
  embed_kernel<<<(M_ * D_) / 256, 256, 0, stream>>>(decode_input, word_emb, f_core, core_bf);

  for (int l = 0; l < L_; ++l) {
    castTo(stream, qkv_w + (size_t)l * 3 * D_ * D_, wl_qkv, (size_t)3 * D_ * D_);
    castTo(stream, r_w + (size_t)l * D_ * D_, wl_r, (size_t)D_ * D_);
    castTo(stream, o_w + (size_t)l * D_ * D_, wl_o, (size_t)D_ * D_);
    castTo(stream, kv_w + (size_t)l * 2 * D_ * D_, wl_kv, (size_t)2 * D_ * D_);
    castTo(stream, q_w + (size_t)l * D_ * D_, wl_q, (size_t)D_ * D_);
    castTo(stream, io_w + (size_t)l * D_ * D_, wl_io, (size_t)D_ * D_);
    castTo(stream, ffn_w1 + (size_t)l * FF_ * D_, wl_f1, (size_t)FF_ * D_);
    castTo(stream, ffn_w2 + (size_t)l * FF_ * D_, wl_f2, (size_t)FF_ * D_);

    // self-attention
    gw(stream, 1, core_bf, wl_qkv, nullptr, heads_bf, M_, 3 * D_, D_, D_, 0, D_, 0, 3 * D_, 0, 1, 1, 0);
    gw(stream, 1, r_bf, wl_r, nullptr, rkproj_bf, S_, D_, D_, D_, 0, D_, 0, D_, 0, 1, 1, 0);
    attn1_fused_kernel<<<B_ * H_, 256, 0, stream>>>(heads_bf, rkproj_bf,
                                                    rw_bias + (size_t)l * D_,
                                                    rr_bias + (size_t)l * D_, attnA_bf);
    gw(stream, 0, attnA_bf, wl_o, nullptr, f_tmp, M_, D_, D_, D_, 0, D_, 0, D_, 0, 1, 2,
       (long long)M_ * D_);
    addln_kernel<<<M_, 256, 0, stream>>>(f_core, f_tmp, 2, (long long)M_ * D_, nullptr,
                                         ln1_g + (size_t)l * D_, ln1_b + (size_t)l * D_, f_x, x_bf);

    // cross-attention
    gw(stream, 1, encT_bf, wl_kv, nullptr, kvproj_bf, ME_, 2 * D_, D_, D_, 0, D_, 0, 2 * D_, 0, 1, 1, 0);
    gw(stream, 0, x_bf, wl_q, nullptr, f_q, M_, D_, D_, D_, 0, D_, 0, D_, 0, 1, 2,
       (long long)M_ * D_);
    attn2_fused_kernel<<<B_ * H_, 256, 0, stream>>>(f_q, f_q + (size_t)M_ * D_, kvproj_bf,
                                                    input_mask, attnA_bf);
    gw(stream, 0, attnA_bf, wl_io, nullptr, f_tmp, M_, D_, D_, D_, 0, D_, 0, D_, 0, 1, 2,
       (long long)M_ * D_);
    addln_kernel<<<M_, 256, 0, stream>>>(f_x, f_tmp, 2, (long long)M_ * D_, nullptr,
                                         ln2_g + (size_t)l * D_, ln2_b + (size_t)l * D_, f_y, y_bf);

    // FFN
    gw(stream, 4, y_bf, wl_f1, ffn_b1 + (size_t)l * FF_, ffnh_bf, M_, FF_, D_, D_, 0, D_, 0, FF_, 0, 1, 1, 0);
    gw(stream, 0, ffnh_bf, wl_f2, nullptr, f_tmp, M_, D_, FF_, FF_, 0, FF_, 0, D_, 0, 1, 4,
       (long long)M_ * D_);
    addln_kernel<<<M_, 256, 0, stream>>>(f_y, f_tmp, 4, (long long)M_ * D_,
                                         ffn_b2 + (size_t)l * D_,
                                         ln3_g + (size_t)l * D_, ln3_b + (size_t)l * D_, f_core, core_bf);
  }

  // merged output+copy head GEMM: [M,2048]
  gw(stream, 3, core_bf, w_oc, b_oc, headout_bf, M_, 2048, D_, D_, 0, D_, 0, 2048, 0, 1, 1, 0);
  mode_kernel<<<M_, 256, 0, stream>>>(f_core, mode_w, mode_b, f_mode);

  // vocab softmax stats (row-tiles fast for B reuse)
  vocab_kernel<<<dim3(M_ / 128, V_ / 128), 256, 0, stream>>>(headout_bf, w_emb, f_tmax, f_tsum);
  vocab_combine_kernel<<<M_, 256, 0, stream>>>(f_tmax, f_tsum, f_rmax, f_rsum);
  tlogit_kernel<<<M_, 256, 0, stream>>>(headout_bf, w_emb, decode_target, f_tlogit);

  // copy logits: batched over b, split-K 4
  gw(stream, 0, headout_bf + D_, enc_bf, nullptr, f_lg, S_, E_, D_,
     (long long)B_ * 2048, 2048, D_, (long long)E_ * D_, E_, (long long)S_ * E_, B_, 4,
     (long long)B_ * S_ * E_);

  hipMemsetAsync(f_loss, 0, 2 * sizeof(float), stream);
  final_kernel<<<dim3(S_, B_), 256, 0, stream>>>(f_lg, input_ids, input_mask, decode_target,
                                                 f_mode, f_tlogit, f_rmax, f_rsum, f_loss);
  writeout_kernel<<<1, 64, 0, stream>>>(f_loss, out);
}